// Round 1
// baseline (6138.399 us; speedup 1.0000x reference)
//
#include <hip/hip_runtime.h>

typedef __attribute__((ext_vector_type(8))) short s8v;
typedef __attribute__((ext_vector_type(4))) float f4v;
using u16 = unsigned short;

__device__ __forceinline__ u16 f2bf(float f) {
  union { float f; unsigned u; } v; v.f = f;
  return (u16)((v.u + 0x7FFFu + ((v.u >> 16) & 1u)) >> 16);
}

// ---------------- positional encoding: pe[256][512] ----------------
__global__ __launch_bounds__(256) void pe_kernel(float* __restrict__ pe) {
  int i = blockIdx.x * 256 + threadIdx.x;   // 65536 = 256 t * 256 pairs
  int t = i >> 8, p = i & 255;
  float ex = (2.f * (float)p) / 512.f;
  float ang = (float)t * expf(-ex * 9.210340371976184f);  // 10000^-ex
  pe[t * 512 + 2 * p]     = sinf(ang);
  pe[t * 512 + 2 * p + 1] = cosf(ang);
}

// -------- weight convert: f32 [R][C] -> bf16 [C][R], batched over z --------
__global__ __launch_bounds__(256) void wconv_kernel(const float* __restrict__ in,
                                                    u16* __restrict__ out, int R, int C) {
  __shared__ float tile[64][65];
  const size_t mat = (size_t)R * C;
  const float* src = in + (size_t)blockIdx.z * mat;
  u16* dst = out + (size_t)blockIdx.z * mat;
  int r0 = blockIdx.x * 64, c0 = blockIdx.y * 64;
  int tr = threadIdx.x >> 6, tc = threadIdx.x & 63;
#pragma unroll
  for (int i = 0; i < 16; ++i)
    tile[i * 4 + tr][tc] = src[(size_t)(r0 + i * 4 + tr) * C + (c0 + tc)];
  __syncthreads();
#pragma unroll
  for (int i = 0; i < 16; ++i)
    dst[(size_t)(c0 + i * 4 + tr) * R + (r0 + tc)] = f2bf(tile[tc][i * 4 + tr]);
}

// ---------------- embedding + pe: y[row][512] f32 ----------------
__global__ __launch_bounds__(256) void embed_kernel(const int* __restrict__ idx,
    const float* __restrict__ emb, const float* __restrict__ pe, float* __restrict__ y) {
  int i = blockIdx.x * 256 + threadIdx.x;   // 16384 rows * 128 thread-chunks
  int row = i >> 7, c = (i & 127) * 4;
  int t = row & 255;
  int tok = idx[row];
  f4v e = *(const f4v*)(emb + (size_t)tok * 512 + c);
  f4v p = *(const f4v*)(pe + (size_t)t * 512 + c);
  *(f4v*)(y + (size_t)row * 512 + c) = e + p;
}

// ---------------- LayerNorm f32 -> bf16, wave per row ----------------
__global__ __launch_bounds__(256) void ln_kernel(const float* __restrict__ x,
    const float* __restrict__ g, const float* __restrict__ b, u16* __restrict__ out) {
  int row = blockIdx.x * 4 + (threadIdx.x >> 6);
  int lane = threadIdx.x & 63;
  const float* xr = x + (size_t)row * 512 + lane * 8;
  f4v v0 = *(const f4v*)xr;
  f4v v1 = *(const f4v*)(xr + 4);
  float s = v0[0] + v0[1] + v0[2] + v0[3] + v1[0] + v1[1] + v1[2] + v1[3];
#pragma unroll
  for (int o = 1; o < 64; o <<= 1) s += __shfl_xor(s, o);
  float mu = s * (1.f / 512.f);
  float q = 0.f;
#pragma unroll
  for (int j = 0; j < 4; ++j) {
    float d0 = v0[j] - mu; q += d0 * d0;
    float d1 = v1[j] - mu; q += d1 * d1;
  }
#pragma unroll
  for (int o = 1; o < 64; o <<= 1) q += __shfl_xor(q, o);
  float rs = rsqrtf(q * (1.f / 512.f) + 1e-5f);
  f4v g0 = *(const f4v*)(g + lane * 8), g1 = *(const f4v*)(g + lane * 8 + 4);
  f4v b0 = *(const f4v*)(b + lane * 8), b1 = *(const f4v*)(b + lane * 8 + 4);
  s8v ov;
#pragma unroll
  for (int j = 0; j < 4; ++j) {
    ov[j]     = (short)f2bf((v0[j] - mu) * rs * g0[j] + b0[j]);
    ov[4 + j] = (short)f2bf((v1[j] - mu) * rs * g1[j] + b1[j]);
  }
  *(s8v*)(out + (size_t)row * 512 + lane * 8) = ov;
}

// ---------------- GEMM: C[M,N] = A[M,K](bf16) @ Bt[N,K](bf16)^T ----------------
// 128x128 tile, BK=64, 4 waves x (64x64), global_load_lds staging (m97 pattern).
template<int HAS_BIAS, int ADD_RES, int RELU, int OUT_BF16>
__global__ __launch_bounds__(256) void gemm_kernel(
    const u16* __restrict__ A, const u16* __restrict__ Bt,
    const float* __restrict__ bias, const float* __restrict__ res,
    void* __restrict__ outp, int M, int N, int K) {
  __shared__ __align__(16) u16 As[128 * 64];
  __shared__ __align__(16) u16 Bs[128 * 64];
  const int tid = threadIdx.x, lane = tid & 63, w = tid >> 6;
  const int m0 = blockIdx.x * 128, n0 = blockIdx.y * 128;
  const int wm = (w >> 1) * 64, wn = (w & 1) * 64;
  const int lhi = lane >> 4, llo = lane & 15;
  const int srow = lane >> 3, scol = (lane & 7) * 8;
  f4v acc[4][4] = {};
  for (int kt = 0; kt < K; kt += 64) {
#pragma unroll
    for (int q = 0; q < 4; ++q) {
      int blkr = (w * 4 + q) * 8;  // 8 rows (128B each) per wave-instr
      __builtin_amdgcn_global_load_lds(
          (const __attribute__((address_space(1))) void*)(A + (size_t)(m0 + blkr + srow) * K + kt + scol),
          (__attribute__((address_space(3))) void*)(As + blkr * 64), 16, 0, 0);
      __builtin_amdgcn_global_load_lds(
          (const __attribute__((address_space(1))) void*)(Bt + (size_t)(n0 + blkr + srow) * K + kt + scol),
          (__attribute__((address_space(3))) void*)(Bs + blkr * 64), 16, 0, 0);
    }
    __syncthreads();
#pragma unroll
    for (int kk = 0; kk < 2; ++kk) {
      s8v af[4], bfr[4];
#pragma unroll
      for (int i = 0; i < 4; ++i)
        af[i] = *(const s8v*)&As[(wm + i * 16 + llo) * 64 + kk * 32 + lhi * 8];
#pragma unroll
      for (int j = 0; j < 4; ++j)
        bfr[j] = *(const s8v*)&Bs[(wn + j * 16 + llo) * 64 + kk * 32 + lhi * 8];
#pragma unroll
      for (int i = 0; i < 4; ++i)
#pragma unroll
        for (int j = 0; j < 4; ++j)
          acc[i][j] = __builtin_amdgcn_mfma_f32_16x16x32_bf16(af[i], bfr[j], acc[i][j], 0, 0, 0);
    }
    __syncthreads();
  }
  // epilogue: D row = (l>>4)*4 + r, col = l&15  (verified layout)
#pragma unroll
  for (int i = 0; i < 4; ++i) {
#pragma unroll
    for (int j = 0; j < 4; ++j) {
      int col = n0 + wn + j * 16 + llo;
      float bv = 0.f;
      if (HAS_BIAS) bv = bias[col];
#pragma unroll
      for (int r = 0; r < 4; ++r) {
        int row = m0 + wm + i * 16 + lhi * 4 + r;
        float v = acc[i][j][r] + bv;
        if (ADD_RES) v += res[(size_t)row * N + col];
        if (RELU) v = fmaxf(v, 0.f);
        if (OUT_BF16) ((u16*)outp)[(size_t)row * N + col] = f2bf(v);
        else          ((float*)outp)[(size_t)row * N + col] = v;
      }
    }
  }
}

// ---------------- fused attention, one (b,h) per block, T=256, hd=64 ----------------
__global__ __launch_bounds__(256) void attn_kernel(
    const u16* __restrict__ Qb, const u16* __restrict__ Kb, const u16* __restrict__ Vb,
    u16* __restrict__ Ob, int causal) {
  __shared__ __align__(16) u16 Ks[256][72];      // K[t][d], padded
  __shared__ __align__(16) u16 Vt[64][264];      // V^T[d][t], padded
  __shared__ __align__(16) u16 Ps[4][16][264];   // per-wave P tile
  const int tid = threadIdx.x, lane = tid & 63, w = tid >> 6;
  const int b = blockIdx.x >> 3, h = blockIdx.x & 7;
  const size_t base = (size_t)b * 256 * 512 + (size_t)h * 64;
  {
    int t0 = tid >> 3, d0 = (tid & 7) * 8;
#pragma unroll
    for (int it = 0; it < 8; ++it) {
      int t = it * 32 + t0;
      s8v kv = *(const s8v*)(Kb + base + (size_t)t * 512 + d0);
      *(s8v*)&Ks[t][d0] = kv;
      s8v vv = *(const s8v*)(Vb + base + (size_t)t * 512 + d0);
#pragma unroll
      for (int j = 0; j < 8; ++j) Vt[d0 + j][t] = (u16)vv[j];
    }
  }
  __syncthreads();
  const int lhi = lane >> 4, llo = lane & 15;
  for (int qc = 0; qc < 4; ++qc) {
    const int qr0 = w * 64 + qc * 16;   // 16 q-rows per wave per chunk
    s8v aq0 = *(const s8v*)(Qb + base + (size_t)(qr0 + llo) * 512 + lhi * 8);
    s8v aq1 = *(const s8v*)(Qb + base + (size_t)(qr0 + llo) * 512 + 32 + lhi * 8);
    f4v S[16];
#pragma unroll
    for (int c = 0; c < 16; ++c) {
      s8v bk0 = *(const s8v*)&Ks[c * 16 + llo][lhi * 8];
      s8v bk1 = *(const s8v*)&Ks[c * 16 + llo][32 + lhi * 8];
      f4v z = {0.f, 0.f, 0.f, 0.f};
      z = __builtin_amdgcn_mfma_f32_16x16x32_bf16(aq0, bk0, z, 0, 0, 0);
      S[c] = __builtin_amdgcn_mfma_f32_16x16x32_bf16(aq1, bk1, z, 0, 0, 0);
    }
#pragma unroll
    for (int r = 0; r < 4; ++r) {
      const int tq = qr0 + lhi * 4 + r;
      float mx = -1e30f;
#pragma unroll
      for (int c = 0; c < 16; ++c) {
        float s = S[c][r] * 0.125f;
        if (causal && (c * 16 + llo) > tq) s = -1e30f;
        S[c][r] = s;
        mx = fmaxf(mx, s);
      }
      mx = fmaxf(mx, __shfl_xor(mx, 1));
      mx = fmaxf(mx, __shfl_xor(mx, 2));
      mx = fmaxf(mx, __shfl_xor(mx, 4));
      mx = fmaxf(mx, __shfl_xor(mx, 8));
      float sum = 0.f;
#pragma unroll
      for (int c = 0; c < 16; ++c) { float p = __expf(S[c][r] - mx); S[c][r] = p; sum += p; }
      sum += __shfl_xor(sum, 1); sum += __shfl_xor(sum, 2);
      sum += __shfl_xor(sum, 4); sum += __shfl_xor(sum, 8);
      float inv = 1.f / sum;
#pragma unroll
      for (int c = 0; c < 16; ++c)
        Ps[w][lhi * 4 + r][c * 16 + llo] = f2bf(S[c][r] * inv);
    }
    asm volatile("s_waitcnt lgkmcnt(0)" ::: "memory");
    f4v o[4] = {};
#pragma unroll
    for (int kb = 0; kb < 8; ++kb) {
      s8v pa = *(const s8v*)&Ps[w][llo][kb * 32 + lhi * 8];
#pragma unroll
      for (int nb = 0; nb < 4; ++nb) {
        s8v bv = *(const s8v*)&Vt[nb * 16 + llo][kb * 32 + lhi * 8];
        o[nb] = __builtin_amdgcn_mfma_f32_16x16x32_bf16(pa, bv, o[nb], 0, 0, 0);
      }
    }
#pragma unroll
    for (int nb = 0; nb < 4; ++nb)
#pragma unroll
      for (int r = 0; r < 4; ++r)
        Ob[base + (size_t)(qr0 + lhi * 4 + r) * 512 + nb * 16 + llo] = f2bf(o[nb][r]);
  }
}

// ---------------- cross-entropy: per-row logsumexp ----------------
__global__ __launch_bounds__(256) void loss_row_kernel(const float* __restrict__ logits,
    const int* __restrict__ tgt, float* __restrict__ nll, float* __restrict__ valid) {
  const int row = blockIdx.x, tid = threadIdx.x;
  const float* lr = logits + (size_t)row * 32000;
  float m = -1e30f, s = 0.f;
  for (int c = tid; c < 32000; c += 256) {
    float x = lr[c];
    if (x > m) { s = s * __expf(m - x) + 1.f; m = x; }
    else        s += __expf(x - m);
  }
  __shared__ float sm[256], ss[256];
  sm[tid] = m; ss[tid] = s;
  __syncthreads();
  for (int st = 128; st > 0; st >>= 1) {
    if (tid < st) {
      float m2 = sm[tid + st], s2 = ss[tid + st];
      float mm = fmaxf(sm[tid], m2);
      ss[tid] = ss[tid] * __expf(sm[tid] - mm) + s2 * __expf(m2 - mm);
      sm[tid] = mm;
    }
    __syncthreads();
  }
  if (tid == 0) {
    int t = tgt[row];
    float lse = sm[0] + logf(ss[0]);
    float v = (t != 1) ? 1.f : 0.f;
    nll[row] = v * (lse - lr[t]);
    valid[row] = v;
  }
}

__global__ __launch_bounds__(256) void loss_final_kernel(const float* __restrict__ nll,
    const float* __restrict__ valid, float* __restrict__ out) {
  __shared__ float sa[256], sb[256];
  int tid = threadIdx.x;
  float s = 0.f, c = 0.f;
  for (int i = tid; i < 16384; i += 256) { s += nll[i]; c += valid[i]; }
  sa[tid] = s; sb[tid] = c;
  __syncthreads();
  for (int st = 128; st > 0; st >>= 1) {
    if (tid < st) { sa[tid] += sa[tid + st]; sb[tid] += sb[tid + st]; }
    __syncthreads();
  }
  if (tid == 0) out[0] = sa[0] / fmaxf(sb[0], 1.f);
}

// =============================== host ===============================
extern "C" void kernel_launch(void* const* d_in, const int* in_sizes, int n_in,
                              void* d_out, int out_size, void* d_ws, size_t ws_size,
                              hipStream_t stream) {
  (void)in_sizes; (void)n_in; (void)out_size; (void)ws_size;
  const int* idx       = (const int*)d_in[0];
  const int* idx_enc   = (const int*)d_in[1];
  const int* targets   = (const int*)d_in[2];
  const float* emb_dec = (const float*)d_in[3];
  const float* emb_enc = (const float*)d_in[4];
  const float* enc_Wq  = (const float*)d_in[5];
  const float* enc_Wk  = (const float*)d_in[6];
  const float* enc_Wv  = (const float*)d_in[7];
  const float* enc_Wo  = (const float*)d_in[8];
  const float* enc_bo  = (const float*)d_in[9];
  const float* enc_ln_g = (const float*)d_in[10];
  const float* enc_ln_b = (const float*)d_in[11];
  const float* enc_W1  = (const float*)d_in[12];
  const float* enc_b1  = (const float*)d_in[13];
  const float* enc_W2  = (const float*)d_in[14];
  const float* enc_b2  = (const float*)d_in[15];
  const float* dWq_sa  = (const float*)d_in[16];
  const float* dWk_sa  = (const float*)d_in[17];
  const float* dWv_sa  = (const float*)d_in[18];
  const float* dWo_sa  = (const float*)d_in[19];
  const float* dbo_sa  = (const float*)d_in[20];
  const float* dWq_xa  = (const float*)d_in[21];
  const float* dWk_xa  = (const float*)d_in[22];
  const float* dWv_xa  = (const float*)d_in[23];
  const float* dWo_xa  = (const float*)d_in[24];
  const float* dbo_xa  = (const float*)d_in[25];
  const float* dec_ln_g = (const float*)d_in[26];
  const float* dec_ln_b = (const float*)d_in[27];
  const float* dec_W1  = (const float*)d_in[28];
  const float* dec_b1  = (const float*)d_in[29];
  const float* dec_W2  = (const float*)d_in[30];
  const float* dec_b2  = (const float*)d_in[31];
  const float* lnf_g   = (const float*)d_in[32];
  const float* lnf_b   = (const float*)d_in[33];
  const float* Wlm     = (const float*)d_in[34];
  const float* blm     = (const float*)d_in[35];
  float* out_logits = (float*)d_out;
  float* out_loss   = out_logits + (size_t)16384 * 32000;

  size_t off = 0;
  auto alloc = [&](size_t bytes) -> char* {
    char* p = (char*)d_ws + off;
    off += (bytes + 255) & ~(size_t)255;
    return p;
  };
  const size_t SQ = 512 * 512, SF = 512 * 2048;
  u16* tWqE = (u16*)alloc(6 * SQ * 2);
  u16* tWkE = (u16*)alloc(6 * SQ * 2);
  u16* tWvE = (u16*)alloc(6 * SQ * 2);
  u16* tWoE = (u16*)alloc(6 * SQ * 2);
  u16* tW1E = (u16*)alloc(6 * SF * 2);
  u16* tW2E = (u16*)alloc(6 * SF * 2);
  u16* tWqS = (u16*)alloc(6 * SQ * 2);
  u16* tWkS = (u16*)alloc(6 * SQ * 2);
  u16* tWvS = (u16*)alloc(6 * SQ * 2);
  u16* tWoS = (u16*)alloc(6 * SQ * 2);
  u16* tWqX = (u16*)alloc(6 * SQ * 2);
  u16* tWkX = (u16*)alloc(6 * SQ * 2);
  u16* tWvX = (u16*)alloc(6 * SQ * 2);
  u16* tWoX = (u16*)alloc(6 * SQ * 2);
  u16* tW1D = (u16*)alloc(6 * SF * 2);
  u16* tW2D = (u16*)alloc(6 * SF * 2);
  u16* tWlm = (u16*)alloc((size_t)32000 * 512 * 2);
  float* pe   = (float*)alloc(256 * 512 * 4);
  float* yE   = (float*)alloc((size_t)16384 * 512 * 4);
  float* xD   = (float*)alloc((size_t)16384 * 512 * 4);
  u16* hA   = (u16*)alloc((size_t)16384 * 512 * 2);
  u16* hB   = (u16*)alloc((size_t)16384 * 512 * 2);
  u16* qB   = (u16*)alloc((size_t)16384 * 512 * 2);
  u16* kB   = (u16*)alloc((size_t)16384 * 512 * 2);
  u16* vB   = (u16*)alloc((size_t)16384 * 512 * 2);
  u16* atB  = (u16*)alloc((size_t)16384 * 512 * 2);
  u16* midB = (u16*)alloc((size_t)16384 * 2048 * 2);
  float* rnll = (float*)alloc(16384 * 4);
  float* rval = (float*)alloc(16384 * 4);

  // ---- weight conversion (every call; deterministic) ----
  dim3 tb(256);
  wconv_kernel<<<dim3(8, 8, 6), tb, 0, stream>>>(enc_Wq, tWqE, 512, 512);
  wconv_kernel<<<dim3(8, 8, 6), tb, 0, stream>>>(enc_Wk, tWkE, 512, 512);
  wconv_kernel<<<dim3(8, 8, 6), tb, 0, stream>>>(enc_Wv, tWvE, 512, 512);
  wconv_kernel<<<dim3(8, 8, 6), tb, 0, stream>>>(enc_Wo, tWoE, 512, 512);
  wconv_kernel<<<dim3(8, 32, 6), tb, 0, stream>>>(enc_W1, tW1E, 512, 2048);
  wconv_kernel<<<dim3(32, 8, 6), tb, 0, stream>>>(enc_W2, tW2E, 2048, 512);
  wconv_kernel<<<dim3(8, 8, 6), tb, 0, stream>>>(dWq_sa, tWqS, 512, 512);
  wconv_kernel<<<dim3(8, 8, 6), tb, 0, stream>>>(dWk_sa, tWkS, 512, 512);
  wconv_kernel<<<dim3(8, 8, 6), tb, 0, stream>>>(dWv_sa, tWvS, 512, 512);
  wconv_kernel<<<dim3(8, 8, 6), tb, 0, stream>>>(dWo_sa, tWoS, 512, 512);
  wconv_kernel<<<dim3(8, 8, 6), tb, 0, stream>>>(dWq_xa, tWqX, 512, 512);
  wconv_kernel<<<dim3(8, 8, 6), tb, 0, stream>>>(dWk_xa, tWkX, 512, 512);
  wconv_kernel<<<dim3(8, 8, 6), tb, 0, stream>>>(dWv_xa, tWvX, 512, 512);
  wconv_kernel<<<dim3(8, 8, 6), tb, 0, stream>>>(dWo_xa, tWoX, 512, 512);
  wconv_kernel<<<dim3(8, 32, 6), tb, 0, stream>>>(dec_W1, tW1D, 512, 2048);
  wconv_kernel<<<dim3(32, 8, 6), tb, 0, stream>>>(dec_W2, tW2D, 2048, 512);
  wconv_kernel<<<dim3(8, 500, 1), tb, 0, stream>>>(Wlm, tWlm, 512, 32000);
  pe_kernel<<<256, 256, 0, stream>>>(pe);

  auto ln = [&](const float* xin, const float* g, const float* bb, u16* o) {
    ln_kernel<<<4096, 256, 0, stream>>>(xin, g, bb, o);
  };
  auto qkv = [&](const u16* Ap, const u16* Bp, u16* Op) {
    gemm_kernel<0, 0, 0, 1><<<dim3(128, 4), 256, 0, stream>>>(Ap, Bp, nullptr, nullptr, Op, 16384, 512, 512);
  };
  auto proj_res = [&](const u16* Ap, const u16* Bp, const float* bi, float* xr, int K) {
    gemm_kernel<1, 1, 0, 0><<<dim3(128, 4), 256, 0, stream>>>(Ap, Bp, bi, xr, xr, 16384, 512, K);
  };
  auto ffn1 = [&](const u16* Ap, const u16* Bp, const float* bi, u16* Op) {
    gemm_kernel<1, 0, 1, 1><<<dim3(128, 16), 256, 0, stream>>>(Ap, Bp, bi, nullptr, Op, 16384, 2048, 512);
  };

  // ---------------- encoder ----------------
  embed_kernel<<<8192, 256, 0, stream>>>(idx_enc, emb_enc, pe, yE);
  for (int l = 0; l < 6; ++l) {
    ln(yE, enc_ln_g + (l * 2 + 0) * 512, enc_ln_b + (l * 2 + 0) * 512, hA);
    qkv(hA, tWqE + l * SQ, qB);
    qkv(hA, tWkE + l * SQ, kB);
    qkv(hA, tWvE + l * SQ, vB);
    attn_kernel<<<512, 256, 0, stream>>>(qB, kB, vB, atB, 0);
    proj_res(atB, tWoE + l * SQ, enc_bo + l * 512, yE, 512);
    ln(yE, enc_ln_g + (l * 2 + 1) * 512, enc_ln_b + (l * 2 + 1) * 512, hA);
    ffn1(hA, tW1E + l * SF, enc_b1 + l * 2048, midB);
    proj_res(midB, tW2E + l * SF, enc_b2 + l * 512, yE, 2048);
  }

  // ---------------- decoder ----------------
  embed_kernel<<<8192, 256, 0, stream>>>(idx, emb_dec, pe, xD);
  for (int l = 0; l < 6; ++l) {
    ln(xD, dec_ln_g + (l * 4 + 0) * 512, dec_ln_b + (l * 4 + 0) * 512, hA);
    qkv(hA, tWqS + l * SQ, qB);
    qkv(hA, tWkS + l * SQ, kB);
    qkv(hA, tWvS + l * SQ, vB);
    attn_kernel<<<512, 256, 0, stream>>>(qB, kB, vB, atB, 1);
    proj_res(atB, tWoS + l * SQ, dbo_sa + l * 512, xD, 512);
    ln(xD, dec_ln_g + (l * 4 + 1) * 512, dec_ln_b + (l * 4 + 1) * 512, hA);
    ln(yE, dec_ln_g + (l * 4 + 2) * 512, dec_ln_b + (l * 4 + 2) * 512, hB);
    qkv(hA, tWqX + l * SQ, qB);
    qkv(hB, tWkX + l * SQ, kB);
    qkv(hB, tWvX + l * SQ, vB);
    attn_kernel<<<512, 256, 0, stream>>>(qB, kB, vB, atB, 0);
    proj_res(atB, tWoX + l * SQ, dbo_xa + l * 512, xD, 512);
    ln(xD, dec_ln_g + (l * 4 + 3) * 512, dec_ln_b + (l * 4 + 3) * 512, hA);
    ffn1(hA, tW1D + l * SF, dec_b1 + l * 2048, midB);
    proj_res(midB, tW2D + l * SF, dec_b2 + l * 512, xD, 2048);
  }

  // ---------------- LM head + loss ----------------
  ln(xD, lnf_g, lnf_b, hA);
  gemm_kernel<1, 0, 0, 0><<<dim3(128, 250), 256, 0, stream>>>(hA, tWlm, blm, nullptr,
                                                              out_logits, 16384, 32000, 512);
  loss_row_kernel<<<16384, 256, 0, stream>>>(out_logits, targets, rnll, rval);
  loss_final_kernel<<<1, 256, 0, stream>>>(rnll, rval, out_loss);
}

// Round 2
// 5805.893 us; speedup vs baseline: 1.0573x; 1.0573x over previous
//
#include <hip/hip_runtime.h>

typedef __attribute__((ext_vector_type(8))) short s8v;
typedef __attribute__((ext_vector_type(4))) float f4v;
using u16 = unsigned short;

__device__ __forceinline__ u16 f2bf(float f) {
  union { float f; unsigned u; } v; v.f = f;
  return (u16)((v.u + 0x7FFFu + ((v.u >> 16) & 1u)) >> 16);
}

// ---------------- positional encoding: pe[256][512] ----------------
__global__ __launch_bounds__(256) void pe_kernel(float* __restrict__ pe) {
  int i = blockIdx.x * 256 + threadIdx.x;   // 65536 = 256 t * 256 pairs
  int t = i >> 8, p = i & 255;
  float ex = (2.f * (float)p) / 512.f;
  float ang = (float)t * expf(-ex * 9.210340371976184f);  // 10000^-ex
  pe[t * 512 + 2 * p]     = sinf(ang);
  pe[t * 512 + 2 * p + 1] = cosf(ang);
}

// -------- weight convert: f32 [R][C] -> bf16 [C][R], z-batched, dst stride --
__global__ __launch_bounds__(256) void wconv_kernel(const float* __restrict__ in,
    u16* __restrict__ out, int R, int C, size_t dstride) {
  __shared__ float tile[64][65];
  const size_t mat = (size_t)R * C;
  const float* src = in + (size_t)blockIdx.z * mat;
  u16* dst = out + (size_t)blockIdx.z * dstride;
  int r0 = blockIdx.x * 64, c0 = blockIdx.y * 64;
  int tr = threadIdx.x >> 6, tc = threadIdx.x & 63;
#pragma unroll
  for (int i = 0; i < 16; ++i)
    tile[i * 4 + tr][tc] = src[(size_t)(r0 + i * 4 + tr) * C + (c0 + tc)];
  __syncthreads();
#pragma unroll
  for (int i = 0; i < 16; ++i)
    dst[(size_t)(c0 + i * 4 + tr) * R + (r0 + tc)] = f2bf(tile[tc][i * 4 + tr]);
}

// ---------------- embedding + pe: y[row][512] f32 ----------------
__global__ __launch_bounds__(256) void embed_kernel(const int* __restrict__ idx,
    const float* __restrict__ emb, const float* __restrict__ pe, float* __restrict__ y) {
  int i = blockIdx.x * 256 + threadIdx.x;
  int row = i >> 7, c = (i & 127) * 4;
  int t = row & 255;
  int tok = idx[row];
  f4v e = *(const f4v*)(emb + (size_t)tok * 512 + c);
  f4v p = *(const f4v*)(pe + (size_t)t * 512 + c);
  *(f4v*)(y + (size_t)row * 512 + c) = e + p;
}

// ---------------- LayerNorm f32 -> bf16, wave per row ----------------
__global__ __launch_bounds__(256) void ln_kernel(const float* __restrict__ x,
    const float* __restrict__ g, const float* __restrict__ b, u16* __restrict__ out) {
  int row = blockIdx.x * 4 + (threadIdx.x >> 6);
  int lane = threadIdx.x & 63;
  const float* xr = x + (size_t)row * 512 + lane * 8;
  f4v v0 = *(const f4v*)xr;
  f4v v1 = *(const f4v*)(xr + 4);
  float s = v0[0] + v0[1] + v0[2] + v0[3] + v1[0] + v1[1] + v1[2] + v1[3];
#pragma unroll
  for (int o = 1; o < 64; o <<= 1) s += __shfl_xor(s, o);
  float mu = s * (1.f / 512.f);
  float q = 0.f;
#pragma unroll
  for (int j = 0; j < 4; ++j) {
    float d0 = v0[j] - mu; q += d0 * d0;
    float d1 = v1[j] - mu; q += d1 * d1;
  }
#pragma unroll
  for (int o = 1; o < 64; o <<= 1) q += __shfl_xor(q, o);
  float rs = rsqrtf(q * (1.f / 512.f) + 1e-5f);
  f4v g0 = *(const f4v*)(g + lane * 8), g1 = *(const f4v*)(g + lane * 8 + 4);
  f4v b0 = *(const f4v*)(b + lane * 8), b1 = *(const f4v*)(b + lane * 8 + 4);
  s8v ov;
#pragma unroll
  for (int j = 0; j < 4; ++j) {
    ov[j]     = (short)f2bf((v0[j] - mu) * rs * g0[j] + b0[j]);
    ov[4 + j] = (short)f2bf((v1[j] - mu) * rs * g1[j] + b1[j]);
  }
  *(s8v*)(out + (size_t)row * 512 + lane * 8) = ov;
}

// ---------------- GEMM: C[M,N] = A[M,K](bf16) @ Bt[N,K](bf16)^T ----------------
// 128x128 tile, BK=64, 4 waves x (64x64), global_load_lds staging (m97 pattern).
// WLOSS: also emit per-row (max, sumexp) partials over this block's 128 cols.
template<int HAS_BIAS, int ADD_RES, int RELU, int OUT_BF16, int WLOSS, int SWZ>
__global__ __launch_bounds__(256) void gemm_kernel(
    const u16* __restrict__ A, const u16* __restrict__ Bt,
    const float* __restrict__ bias, const float* __restrict__ res,
    void* __restrict__ outp, int M, int N, int K,
    float* __restrict__ pmax, float* __restrict__ psum) {
  __shared__ __align__(16) u16 As[128 * 64];
  __shared__ __align__(16) u16 Bs[128 * 64];
  const int tid = threadIdx.x, lane = tid & 63, w = tid >> 6;
  int bx = blockIdx.x, by = blockIdx.y;
  if (SWZ) {
    int nx = gridDim.x;
    int flat = by * nx + bx;
    int per = (nx * gridDim.y) >> 3;
    int s = (flat & 7) * per + (flat >> 3);
    by = s / nx; bx = s - by * nx;
  }
  const int m0 = bx * 128, n0 = by * 128;
  const int wm = (w >> 1) * 64, wn = (w & 1) * 64;
  const int lhi = lane >> 4, llo = lane & 15;
  const int srow = lane >> 3, scol = (lane & 7) * 8;
  f4v acc[4][4] = {};
  for (int kt = 0; kt < K; kt += 64) {
#pragma unroll
    for (int q = 0; q < 4; ++q) {
      int blkr = (w * 4 + q) * 8;
      __builtin_amdgcn_global_load_lds(
          (const __attribute__((address_space(1))) void*)(A + (size_t)(m0 + blkr + srow) * K + kt + scol),
          (__attribute__((address_space(3))) void*)(As + blkr * 64), 16, 0, 0);
      __builtin_amdgcn_global_load_lds(
          (const __attribute__((address_space(1))) void*)(Bt + (size_t)(n0 + blkr + srow) * K + kt + scol),
          (__attribute__((address_space(3))) void*)(Bs + blkr * 64), 16, 0, 0);
    }
    __syncthreads();
#pragma unroll
    for (int kk = 0; kk < 2; ++kk) {
      s8v af[4], bfr[4];
#pragma unroll
      for (int i = 0; i < 4; ++i)
        af[i] = *(const s8v*)&As[(wm + i * 16 + llo) * 64 + kk * 32 + lhi * 8];
#pragma unroll
      for (int j = 0; j < 4; ++j)
        bfr[j] = *(const s8v*)&Bs[(wn + j * 16 + llo) * 64 + kk * 32 + lhi * 8];
#pragma unroll
      for (int i = 0; i < 4; ++i)
#pragma unroll
        for (int j = 0; j < 4; ++j)
          acc[i][j] = __builtin_amdgcn_mfma_f32_16x16x32_bf16(af[i], bfr[j], acc[i][j], 0, 0, 0);
    }
    __syncthreads();
  }
  // epilogue: D row = (l>>4)*4 + r, col = l&15  (verified layout)
  float bvj[4];
#pragma unroll
  for (int j = 0; j < 4; ++j)
    bvj[j] = HAS_BIAS ? bias[n0 + wn + j * 16 + llo] : 0.f;
#pragma unroll
  for (int i = 0; i < 4; ++i) {
#pragma unroll
    for (int j = 0; j < 4; ++j) {
      int col = n0 + wn + j * 16 + llo;
#pragma unroll
      for (int r = 0; r < 4; ++r) {
        int row = m0 + wm + i * 16 + lhi * 4 + r;
        float v = acc[i][j][r] + bvj[j];
        if (ADD_RES) v += res[(size_t)row * N + col];
        if (RELU) v = fmaxf(v, 0.f);
        if (OUT_BF16) ((u16*)outp)[(size_t)row * N + col] = f2bf(v);
        else          ((float*)outp)[(size_t)row * N + col] = v;
      }
    }
  }
  if (WLOSS) {
    float* lbuf = (float*)As;   // safe: all LDS reads done (final barrier in loop)
#pragma unroll
    for (int i = 0; i < 4; ++i) {
#pragma unroll
      for (int r = 0; r < 4; ++r) {
        float mx = -1e30f;
#pragma unroll
        for (int j = 0; j < 4; ++j) mx = fmaxf(mx, acc[i][j][r] + bvj[j]);
        mx = fmaxf(mx, __shfl_xor(mx, 1));
        mx = fmaxf(mx, __shfl_xor(mx, 2));
        mx = fmaxf(mx, __shfl_xor(mx, 4));
        mx = fmaxf(mx, __shfl_xor(mx, 8));
        float sum = 0.f;
#pragma unroll
        for (int j = 0; j < 4; ++j) sum += __expf(acc[i][j][r] + bvj[j] - mx);
        sum += __shfl_xor(sum, 1); sum += __shfl_xor(sum, 2);
        sum += __shfl_xor(sum, 4); sum += __shfl_xor(sum, 8);
        if (llo == 0) {
          int lr = wm + i * 16 + lhi * 4 + r;
          lbuf[lr * 2 + (wn >> 6)] = mx;
          lbuf[256 + lr * 2 + (wn >> 6)] = sum;
        }
      }
    }
    __syncthreads();
    if (tid < 128) {
      float ma = lbuf[tid * 2],       mb = lbuf[tid * 2 + 1];
      float sa = lbuf[256 + tid * 2], sb = lbuf[256 + tid * 2 + 1];
      float mm = fmaxf(ma, mb);
      float ss = sa * __expf(ma - mm) + sb * __expf(mb - mm);
      int nt = N >> 7;
      pmax[(size_t)(m0 + tid) * nt + (n0 >> 7)] = mm;
      psum[(size_t)(m0 + tid) * nt + (n0 >> 7)] = ss;
    }
  }
}

// -------- fused attention, one (b,h) per block, T=256, hd=64, strided QKV ----
__global__ __launch_bounds__(256) void attn_kernel(
    const u16* __restrict__ Qp, int qs, const u16* __restrict__ Kp,
    const u16* __restrict__ Vp, int kvs, u16* __restrict__ Ob, int causal) {
  __shared__ __align__(16) u16 Ks[256][72];      // K[t][d], padded
  __shared__ __align__(16) u16 Vt[64][264];      // V^T[d][t], padded
  __shared__ __align__(16) u16 Ps[4][16][264];   // per-wave P tile
  const int tid = threadIdx.x, lane = tid & 63, w = tid >> 6;
  const int b = blockIdx.x >> 3, h = blockIdx.x & 7;
  const size_t qbase  = (size_t)b * 256 * qs  + (size_t)h * 64;
  const size_t kvbase = (size_t)b * 256 * kvs + (size_t)h * 64;
  const size_t obase  = (size_t)b * 256 * 512 + (size_t)h * 64;
  {
    int t0 = tid >> 3, d0 = (tid & 7) * 8;
#pragma unroll
    for (int it = 0; it < 8; ++it) {
      int t = it * 32 + t0;
      s8v kv = *(const s8v*)(Kp + kvbase + (size_t)t * kvs + d0);
      *(s8v*)&Ks[t][d0] = kv;
      s8v vv = *(const s8v*)(Vp + kvbase + (size_t)t * kvs + d0);
#pragma unroll
      for (int j = 0; j < 8; ++j) Vt[d0 + j][t] = (u16)vv[j];
    }
  }
  __syncthreads();
  const int lhi = lane >> 4, llo = lane & 15;
  for (int qc = 0; qc < 4; ++qc) {
    const int qr0 = w * 64 + qc * 16;
    s8v aq0 = *(const s8v*)(Qp + qbase + (size_t)(qr0 + llo) * qs + lhi * 8);
    s8v aq1 = *(const s8v*)(Qp + qbase + (size_t)(qr0 + llo) * qs + 32 + lhi * 8);
    f4v S[16];
#pragma unroll
    for (int c = 0; c < 16; ++c) {
      s8v bk0 = *(const s8v*)&Ks[c * 16 + llo][lhi * 8];
      s8v bk1 = *(const s8v*)&Ks[c * 16 + llo][32 + lhi * 8];
      f4v z = {0.f, 0.f, 0.f, 0.f};
      z = __builtin_amdgcn_mfma_f32_16x16x32_bf16(aq0, bk0, z, 0, 0, 0);
      S[c] = __builtin_amdgcn_mfma_f32_16x16x32_bf16(aq1, bk1, z, 0, 0, 0);
    }
#pragma unroll
    for (int r = 0; r < 4; ++r) {
      const int tq = qr0 + lhi * 4 + r;
      float mx = -1e30f;
#pragma unroll
      for (int c = 0; c < 16; ++c) {
        float s = S[c][r] * 0.125f;
        if (causal && (c * 16 + llo) > tq) s = -1e30f;
        S[c][r] = s;
        mx = fmaxf(mx, s);
      }
      mx = fmaxf(mx, __shfl_xor(mx, 1));
      mx = fmaxf(mx, __shfl_xor(mx, 2));
      mx = fmaxf(mx, __shfl_xor(mx, 4));
      mx = fmaxf(mx, __shfl_xor(mx, 8));
      float sum = 0.f;
#pragma unroll
      for (int c = 0; c < 16; ++c) { float p = __expf(S[c][r] - mx); S[c][r] = p; sum += p; }
      sum += __shfl_xor(sum, 1); sum += __shfl_xor(sum, 2);
      sum += __shfl_xor(sum, 4); sum += __shfl_xor(sum, 8);
      float inv = 1.f / sum;
#pragma unroll
      for (int c = 0; c < 16; ++c)
        Ps[w][lhi * 4 + r][c * 16 + llo] = f2bf(S[c][r] * inv);
    }
    asm volatile("s_waitcnt lgkmcnt(0)" ::: "memory");
    f4v o[4] = {};
#pragma unroll
    for (int kb = 0; kb < 8; ++kb) {
      s8v pa = *(const s8v*)&Ps[w][llo][kb * 32 + lhi * 8];
#pragma unroll
      for (int nb = 0; nb < 4; ++nb) {
        s8v bv = *(const s8v*)&Vt[nb * 16 + llo][kb * 32 + lhi * 8];
        o[nb] = __builtin_amdgcn_mfma_f32_16x16x32_bf16(pa, bv, o[nb], 0, 0, 0);
      }
    }
#pragma unroll
    for (int nb = 0; nb < 4; ++nb)
#pragma unroll
      for (int r = 0; r < 4; ++r)
        Ob[obase + (size_t)(qr0 + lhi * 4 + r) * 512 + nb * 16 + llo] = f2bf(o[nb][r]);
  }
}

// ---------------- loss: merge per-tile partials -> per-row nll ----------------
__global__ __launch_bounds__(256) void loss_lse_kernel(const float* __restrict__ pmax,
    const float* __restrict__ psum, const float* __restrict__ logits,
    const int* __restrict__ tgt, float* __restrict__ nll, float* __restrict__ valid) {
  const int w = threadIdx.x >> 6, lane = threadIdx.x & 63;
  const int row = blockIdx.x * 4 + w;
  float m = -1e30f, s = 0.f;
  for (int e = lane; e < 250; e += 64) {
    float pm = pmax[(size_t)row * 250 + e], ps = psum[(size_t)row * 250 + e];
    if (pm > m) { s = s * __expf(m - pm) + ps; m = pm; }
    else          s += ps * __expf(pm - m);
  }
#pragma unroll
  for (int o = 1; o < 64; o <<= 1) {
    float om = __shfl_xor(m, o), os = __shfl_xor(s, o);
    float mm = fmaxf(m, om);
    s = s * __expf(m - mm) + os * __expf(om - mm);
    m = mm;
  }
  if (lane == 0) {
    int t = tgt[row];
    float lse = m + logf(s);
    float v = (t != 1) ? 1.f : 0.f;
    nll[row] = v * (lse - logits[(size_t)row * 32000 + t]);
    valid[row] = v;
  }
}

__global__ __launch_bounds__(256) void loss_final_kernel(const float* __restrict__ nll,
    const float* __restrict__ valid, float* __restrict__ out) {
  __shared__ float sa[256], sb[256];
  int tid = threadIdx.x;
  float s = 0.f, c = 0.f;
  for (int i = tid; i < 16384; i += 256) { s += nll[i]; c += valid[i]; }
  sa[tid] = s; sb[tid] = c;
  __syncthreads();
  for (int st = 128; st > 0; st >>= 1) {
    if (tid < st) { sa[tid] += sa[tid + st]; sb[tid] += sb[tid + st]; }
    __syncthreads();
  }
  if (tid == 0) out[0] = sa[0] / fmaxf(sb[0], 1.f);
}

// =============================== host ===============================
extern "C" void kernel_launch(void* const* d_in, const int* in_sizes, int n_in,
                              void* d_out, int out_size, void* d_ws, size_t ws_size,
                              hipStream_t stream) {
  (void)in_sizes; (void)n_in; (void)out_size; (void)ws_size;
  const int* idx       = (const int*)d_in[0];
  const int* idx_enc   = (const int*)d_in[1];
  const int* targets   = (const int*)d_in[2];
  const float* emb_dec = (const float*)d_in[3];
  const float* emb_enc = (const float*)d_in[4];
  const float* enc_Wq  = (const float*)d_in[5];
  const float* enc_Wk  = (const float*)d_in[6];
  const float* enc_Wv  = (const float*)d_in[7];
  const float* enc_Wo  = (const float*)d_in[8];
  const float* enc_bo  = (const float*)d_in[9];
  const float* enc_ln_g = (const float*)d_in[10];
  const float* enc_ln_b = (const float*)d_in[11];
  const float* enc_W1  = (const float*)d_in[12];
  const float* enc_b1  = (const float*)d_in[13];
  const float* enc_W2  = (const float*)d_in[14];
  const float* enc_b2  = (const float*)d_in[15];
  const float* dWq_sa  = (const float*)d_in[16];
  const float* dWk_sa  = (const float*)d_in[17];
  const float* dWv_sa  = (const float*)d_in[18];
  const float* dWo_sa  = (const float*)d_in[19];
  const float* dbo_sa  = (const float*)d_in[20];
  const float* dWq_xa  = (const float*)d_in[21];
  const float* dWk_xa  = (const float*)d_in[22];
  const float* dWv_xa  = (const float*)d_in[23];
  const float* dWo_xa  = (const float*)d_in[24];
  const float* dbo_xa  = (const float*)d_in[25];
  const float* dec_ln_g = (const float*)d_in[26];
  const float* dec_ln_b = (const float*)d_in[27];
  const float* dec_W1  = (const float*)d_in[28];
  const float* dec_b1  = (const float*)d_in[29];
  const float* dec_W2  = (const float*)d_in[30];
  const float* dec_b2  = (const float*)d_in[31];
  const float* lnf_g   = (const float*)d_in[32];
  const float* lnf_b   = (const float*)d_in[33];
  const float* Wlm     = (const float*)d_in[34];
  const float* blm     = (const float*)d_in[35];
  float* out_logits = (float*)d_out;
  float* out_loss   = out_logits + (size_t)16384 * 32000;

  size_t off = 0;
  auto alloc = [&](size_t bytes) -> char* {
    char* p = (char*)d_ws + off;
    off += (bytes + 255) & ~(size_t)255;
    return p;
  };
  const size_t SQ = 512 * 512, SF = 512 * 2048;
  u16* tWqkvE = (u16*)alloc(6 * 3 * SQ * 2);   // per layer: [Wq^T|Wk^T|Wv^T]
  u16* tWoE   = (u16*)alloc(6 * SQ * 2);
  u16* tW1E   = (u16*)alloc(6 * SF * 2);
  u16* tW2E   = (u16*)alloc(6 * SF * 2);
  u16* tWqkvS = (u16*)alloc(6 * 3 * SQ * 2);
  u16* tWoS   = (u16*)alloc(6 * SQ * 2);
  u16* tWqX   = (u16*)alloc(6 * SQ * 2);
  u16* tWkvX  = (u16*)alloc(6 * 2 * SQ * 2);   // per layer: [Wk^T|Wv^T]
  u16* tWoX   = (u16*)alloc(6 * SQ * 2);
  u16* tW1D   = (u16*)alloc(6 * SF * 2);
  u16* tW2D   = (u16*)alloc(6 * SF * 2);
  u16* tWlm   = (u16*)alloc((size_t)32000 * 512 * 2);
  float* pe   = (float*)alloc(256 * 512 * 4);
  float* yE   = (float*)alloc((size_t)16384 * 512 * 4);
  float* xD   = (float*)alloc((size_t)16384 * 512 * 4);
  u16* hA     = (u16*)alloc((size_t)16384 * 512 * 2);
  u16* hB     = (u16*)alloc((size_t)16384 * 512 * 2);
  u16* qkvB   = (u16*)alloc((size_t)16384 * 1536 * 2);
  u16* qB     = (u16*)alloc((size_t)16384 * 512 * 2);
  u16* kvB    = (u16*)alloc((size_t)16384 * 1024 * 2);
  u16* atB    = (u16*)alloc((size_t)16384 * 512 * 2);
  u16* midB   = (u16*)alloc((size_t)16384 * 2048 * 2);
  float* pmax = (float*)alloc((size_t)16384 * 250 * 4);
  float* psum = (float*)alloc((size_t)16384 * 250 * 4);
  float* rnll = (float*)alloc(16384 * 4);
  float* rval = (float*)alloc(16384 * 4);

  // ---- weight conversion (every call; deterministic) ----
  dim3 tb(256);
  const size_t S3 = 3 * SQ, S2 = 2 * SQ;
  wconv_kernel<<<dim3(8, 8, 6), tb, 0, stream>>>(enc_Wq, tWqkvE + 0 * SQ, 512, 512, S3);
  wconv_kernel<<<dim3(8, 8, 6), tb, 0, stream>>>(enc_Wk, tWqkvE + 1 * SQ, 512, 512, S3);
  wconv_kernel<<<dim3(8, 8, 6), tb, 0, stream>>>(enc_Wv, tWqkvE + 2 * SQ, 512, 512, S3);
  wconv_kernel<<<dim3(8, 8, 6), tb, 0, stream>>>(enc_Wo, tWoE, 512, 512, SQ);
  wconv_kernel<<<dim3(8, 32, 6), tb, 0, stream>>>(enc_W1, tW1E, 512, 2048, SF);
  wconv_kernel<<<dim3(32, 8, 6), tb, 0, stream>>>(enc_W2, tW2E, 2048, 512, SF);
  wconv_kernel<<<dim3(8, 8, 6), tb, 0, stream>>>(dWq_sa, tWqkvS + 0 * SQ, 512, 512, S3);
  wconv_kernel<<<dim3(8, 8, 6), tb, 0, stream>>>(dWk_sa, tWqkvS + 1 * SQ, 512, 512, S3);
  wconv_kernel<<<dim3(8, 8, 6), tb, 0, stream>>>(dWv_sa, tWqkvS + 2 * SQ, 512, 512, S3);
  wconv_kernel<<<dim3(8, 8, 6), tb, 0, stream>>>(dWo_sa, tWoS, 512, 512, SQ);
  wconv_kernel<<<dim3(8, 8, 6), tb, 0, stream>>>(dWq_xa, tWqX, 512, 512, SQ);
  wconv_kernel<<<dim3(8, 8, 6), tb, 0, stream>>>(dWk_xa, tWkvX + 0 * SQ, 512, 512, S2);
  wconv_kernel<<<dim3(8, 8, 6), tb, 0, stream>>>(dWv_xa, tWkvX + 1 * SQ, 512, 512, S2);
  wconv_kernel<<<dim3(8, 8, 6), tb, 0, stream>>>(dWo_xa, tWoX, 512, 512, SQ);
  wconv_kernel<<<dim3(8, 32, 6), tb, 0, stream>>>(dec_W1, tW1D, 512, 2048, SF);
  wconv_kernel<<<dim3(32, 8, 6), tb, 0, stream>>>(dec_W2, tW2D, 2048, 512, SF);
  wconv_kernel<<<dim3(8, 500, 1), tb, 0, stream>>>(Wlm, tWlm, 512, 32000, (size_t)0);
  pe_kernel<<<256, 256, 0, stream>>>(pe);

  auto ln = [&](const float* xin, const float* g, const float* bb, u16* o) {
    ln_kernel<<<4096, 256, 0, stream>>>(xin, g, bb, o);
  };
  auto gemm_b16 = [&](const u16* Ap, const u16* Bp, u16* Op, int N) {
    gemm_kernel<0, 0, 0, 1, 0, 0><<<dim3(128, N / 128), 256, 0, stream>>>(
        Ap, Bp, nullptr, nullptr, Op, 16384, N, 512, nullptr, nullptr);
  };
  auto proj_res = [&](const u16* Ap, const u16* Bp, const float* bi, float* xr, int K) {
    gemm_kernel<1, 1, 0, 0, 0, 0><<<dim3(128, 4), 256, 0, stream>>>(
        Ap, Bp, bi, xr, xr, 16384, 512, K, nullptr, nullptr);
  };
  auto ffn1 = [&](const u16* Ap, const u16* Bp, const float* bi, u16* Op) {
    gemm_kernel<1, 0, 1, 1, 0, 0><<<dim3(128, 16), 256, 0, stream>>>(
        Ap, Bp, bi, nullptr, Op, 16384, 2048, 512, nullptr, nullptr);
  };

  // ---------------- encoder ----------------
  embed_kernel<<<8192, 256, 0, stream>>>(idx_enc, emb_enc, pe, yE);
  for (int l = 0; l < 6; ++l) {
    ln(yE, enc_ln_g + (l * 2 + 0) * 512, enc_ln_b + (l * 2 + 0) * 512, hA);
    gemm_b16(hA, tWqkvE + l * S3, qkvB, 1536);
    attn_kernel<<<512, 256, 0, stream>>>(qkvB, 1536, qkvB + 512, qkvB + 1024, 1536, atB, 0);
    proj_res(atB, tWoE + l * SQ, enc_bo + l * 512, yE, 512);
    ln(yE, enc_ln_g + (l * 2 + 1) * 512, enc_ln_b + (l * 2 + 1) * 512, hA);
    ffn1(hA, tW1E + l * SF, enc_b1 + l * 2048, midB);
    proj_res(midB, tW2E + l * SF, enc_b2 + l * 512, yE, 2048);
  }

  // ---------------- decoder ----------------
  embed_kernel<<<8192, 256, 0, stream>>>(idx, emb_dec, pe, xD);
  for (int l = 0; l < 6; ++l) {
    ln(xD, dec_ln_g + (l * 4 + 0) * 512, dec_ln_b + (l * 4 + 0) * 512, hA);
    gemm_b16(hA, tWqkvS + l * S3, qkvB, 1536);
    attn_kernel<<<512, 256, 0, stream>>>(qkvB, 1536, qkvB + 512, qkvB + 1024, 1536, atB, 1);
    proj_res(atB, tWoS + l * SQ, dbo_sa + l * 512, xD, 512);
    ln(xD, dec_ln_g + (l * 4 + 1) * 512, dec_ln_b + (l * 4 + 1) * 512, hA);
    ln(yE, dec_ln_g + (l * 4 + 2) * 512, dec_ln_b + (l * 4 + 2) * 512, hB);
    gemm_b16(hA, tWqX + l * SQ, qB, 512);
    gemm_b16(hB, tWkvX + l * S2, kvB, 1024);
    attn_kernel<<<512, 256, 0, stream>>>(qB, 512, kvB, kvB + 512, 1024, atB, 0);
    proj_res(atB, tWoX + l * SQ, dbo_xa + l * 512, xD, 512);
    ln(xD, dec_ln_g + (l * 4 + 3) * 512, dec_ln_b + (l * 4 + 3) * 512, hA);
    ffn1(hA, tW1D + l * SF, dec_b1 + l * 2048, midB);
    proj_res(midB, tW2D + l * SF, dec_b2 + l * 512, xD, 2048);
  }

  // ---------------- LM head (fused loss partials) + loss ----------------
  ln(xD, lnf_g, lnf_b, hA);
  gemm_kernel<1, 0, 0, 0, 1, 1><<<dim3(128, 250), 256, 0, stream>>>(
      hA, tWlm, blm, nullptr, out_logits, 16384, 32000, 512, pmax, psum);
  loss_lse_kernel<<<4096, 256, 0, stream>>>(pmax, psum, out_logits, targets, rnll, rval);
  loss_final_kernel<<<1, 256, 0, stream>>>(rnll, rval, out_loss);
}

// Round 3
// 5748.092 us; speedup vs baseline: 1.0679x; 1.0101x over previous
//
#include <hip/hip_runtime.h>

typedef __attribute__((ext_vector_type(8))) short s8v;
typedef __attribute__((ext_vector_type(4))) float f4v;
using u16 = unsigned short;

__device__ __forceinline__ u16 f2bf(float f) {
  union { float f; unsigned u; } v; v.f = f;
  return (u16)((v.u + 0x7FFFu + ((v.u >> 16) & 1u)) >> 16);
}

// ---------------- positional encoding: pe[256][512] ----------------
__global__ __launch_bounds__(256) void pe_kernel(float* __restrict__ pe) {
  int i = blockIdx.x * 256 + threadIdx.x;
  int t = i >> 8, p = i & 255;
  float ex = (2.f * (float)p) / 512.f;
  float ang = (float)t * expf(-ex * 9.210340371976184f);
  pe[t * 512 + 2 * p]     = sinf(ang);
  pe[t * 512 + 2 * p + 1] = cosf(ang);
}

// -------- weight convert: f32 [R][C] -> bf16 [C][R], z-batched, dst stride --
__global__ __launch_bounds__(256) void wconv_kernel(const float* __restrict__ in,
    u16* __restrict__ out, int R, int C, size_t dstride) {
  __shared__ float tile[64][65];
  const size_t mat = (size_t)R * C;
  const float* src = in + (size_t)blockIdx.z * mat;
  u16* dst = out + (size_t)blockIdx.z * dstride;
  int r0 = blockIdx.x * 64, c0 = blockIdx.y * 64;
  int tr = threadIdx.x >> 6, tc = threadIdx.x & 63;
#pragma unroll
  for (int i = 0; i < 16; ++i)
    tile[i * 4 + tr][tc] = src[(size_t)(r0 + i * 4 + tr) * C + (c0 + tc)];
  __syncthreads();
#pragma unroll
  for (int i = 0; i < 16; ++i)
    dst[(size_t)(c0 + i * 4 + tr) * R + (r0 + tc)] = f2bf(tile[tc][i * 4 + tr]);
}

// ---------------- embedding + pe ----------------
__global__ __launch_bounds__(256) void embed_kernel(const int* __restrict__ idx,
    const float* __restrict__ emb, const float* __restrict__ pe, float* __restrict__ y) {
  int i = blockIdx.x * 256 + threadIdx.x;
  int row = i >> 7, c = (i & 127) * 4;
  int t = row & 255;
  int tok = idx[row];
  f4v e = *(const f4v*)(emb + (size_t)tok * 512 + c);
  f4v p = *(const f4v*)(pe + (size_t)t * 512 + c);
  *(f4v*)(y + (size_t)row * 512 + c) = e + p;
}

// ---------------- LayerNorm f32 -> bf16, wave per row ----------------
__global__ __launch_bounds__(256) void ln_kernel(const float* __restrict__ x,
    const float* __restrict__ g, const float* __restrict__ b, u16* __restrict__ out) {
  int row = blockIdx.x * 4 + (threadIdx.x >> 6);
  int lane = threadIdx.x & 63;
  const float* xr = x + (size_t)row * 512 + lane * 8;
  f4v v0 = *(const f4v*)xr;
  f4v v1 = *(const f4v*)(xr + 4);
  float s = v0[0] + v0[1] + v0[2] + v0[3] + v1[0] + v1[1] + v1[2] + v1[3];
#pragma unroll
  for (int o = 1; o < 64; o <<= 1) s += __shfl_xor(s, o);
  float mu = s * (1.f / 512.f);
  float q = 0.f;
#pragma unroll
  for (int j = 0; j < 4; ++j) {
    float d0 = v0[j] - mu; q += d0 * d0;
    float d1 = v1[j] - mu; q += d1 * d1;
  }
#pragma unroll
  for (int o = 1; o < 64; o <<= 1) q += __shfl_xor(q, o);
  float rs = rsqrtf(q * (1.f / 512.f) + 1e-5f);
  f4v g0 = *(const f4v*)(g + lane * 8), g1 = *(const f4v*)(g + lane * 8 + 4);
  f4v b0 = *(const f4v*)(b + lane * 8), b1 = *(const f4v*)(b + lane * 8 + 4);
  s8v ov;
#pragma unroll
  for (int j = 0; j < 4; ++j) {
    ov[j]     = (short)f2bf((v0[j] - mu) * rs * g0[j] + b0[j]);
    ov[4 + j] = (short)f2bf((v1[j] - mu) * rs * g1[j] + b1[j]);
  }
  *(s8v*)(out + (size_t)row * 512 + lane * 8) = ov;
}

// ======== GEMM: C[M,N] = A[M,K](bf16) @ Bt[N,K](bf16)^T ========
// 256xBN tile (BN = NR*64), BK=64, 8 waves (2M x 4N), double-buffered LDS,
// T3-minimum 2-phase: STAGE(next) -> compute(cur) -> vmcnt(0)+s_barrier.
template<int NR, int HAS_BIAS, int ADD_RES, int RELU, int OUT_BF16, int WLOSS>
__global__ __launch_bounds__(512, 2) void gemm256_kernel(
    const u16* __restrict__ A, const u16* __restrict__ Bt,
    const float* __restrict__ bias, const float* __restrict__ res,
    void* __restrict__ outp, int M, int N, int K,
    float* __restrict__ pmax, float* __restrict__ psum) {
  __shared__ __align__(16) u16 As[2][256 * 64];
  __shared__ __align__(16) u16 Bs[2][NR * 64 * 64];
  const int tid = threadIdx.x, lane = tid & 63, w = tid >> 6;
  // bijective XCD swizzle (grid always % 8 == 0 here)
  int nx = gridDim.x;
  int flat = blockIdx.y * nx + blockIdx.x;
  int per = (nx * gridDim.y) >> 3;
  int s = (flat & 7) * per + (flat >> 3);
  int by = s / nx, bx = s - by * nx;
  const int m0 = bx * 256, n0 = by * (NR * 64);
  const int wm = (w >> 2) * 128, wn = (w & 3) * (NR * 16);
  const int lhi = lane >> 4, llo = lane & 15;
  const int srow = tid >> 3, scol = (tid & 7) * 8;

  const u16* Ag = A + (size_t)(m0 + srow) * K + scol;
  const u16* Bg = Bt + (size_t)(n0 + srow) * K + scol;
  const size_t rstep = (size_t)64 * K;

  auto STAGE = [&](int b, int kt) {
#pragma unroll
    for (int q = 0; q < 4; ++q)
      __builtin_amdgcn_global_load_lds(
          (const __attribute__((address_space(1))) void*)(Ag + q * rstep + kt),
          (__attribute__((address_space(3))) void*)(&As[b][(q * 64 + srow) * 64 + scol]),
          16, 0, 0);
#pragma unroll
    for (int q = 0; q < NR; ++q)
      __builtin_amdgcn_global_load_lds(
          (const __attribute__((address_space(1))) void*)(Bg + q * rstep + kt),
          (__attribute__((address_space(3))) void*)(&Bs[b][(q * 64 + srow) * 64 + scol]),
          16, 0, 0);
  };

  f4v acc[8][NR] = {};
  const int nk = K >> 6;
  STAGE(0, 0);
  asm volatile("s_waitcnt vmcnt(0)" ::: "memory");
  __builtin_amdgcn_s_barrier();
  __builtin_amdgcn_sched_barrier(0);
  int cur = 0;
  for (int t = 0; t < nk; ++t) {
    if (t + 1 < nk) STAGE(cur ^ 1, (t + 1) * 64);
#pragma unroll
    for (int kk = 0; kk < 2; ++kk) {
      s8v af[8], bfv[NR];
#pragma unroll
      for (int i = 0; i < 8; ++i)
        af[i] = *(const s8v*)&As[cur][(wm + i * 16 + llo) * 64 + kk * 32 + lhi * 8];
#pragma unroll
      for (int j = 0; j < NR; ++j)
        bfv[j] = *(const s8v*)&Bs[cur][(wn + j * 16 + llo) * 64 + kk * 32 + lhi * 8];
#pragma unroll
      for (int i = 0; i < 8; ++i)
#pragma unroll
        for (int j = 0; j < NR; ++j)
          acc[i][j] = __builtin_amdgcn_mfma_f32_16x16x32_bf16(af[i], bfv[j], acc[i][j], 0, 0, 0);
    }
    asm volatile("s_waitcnt vmcnt(0)" ::: "memory");
    __builtin_amdgcn_s_barrier();
    __builtin_amdgcn_sched_barrier(0);
    cur ^= 1;
  }
  // epilogue: D row = (l>>4)*4 + r, col = l&15 (verified layout)
  float bvj[NR];
#pragma unroll
  for (int j = 0; j < NR; ++j)
    bvj[j] = HAS_BIAS ? bias[n0 + wn + j * 16 + llo] : 0.f;
#pragma unroll
  for (int i = 0; i < 8; ++i) {
#pragma unroll
    for (int j = 0; j < NR; ++j) {
      int col = n0 + wn + j * 16 + llo;
#pragma unroll
      for (int r = 0; r < 4; ++r) {
        int row = m0 + wm + i * 16 + lhi * 4 + r;
        float v = acc[i][j][r] + bvj[j];
        if (ADD_RES) v += res[(size_t)row * N + col];
        if (RELU) v = fmaxf(v, 0.f);
        if (OUT_BF16) ((u16*)outp)[(size_t)row * N + col] = f2bf(v);
        else          ((float*)outp)[(size_t)row * N + col] = v;
      }
    }
  }
  if (WLOSS && NR == 4) {
    float* lbm = (float*)&As[0][0];        // 256 rows x 4 wave-cols
    float* lbs = lbm + 1024;
#pragma unroll
    for (int i = 0; i < 8; ++i) {
#pragma unroll
      for (int r = 0; r < 4; ++r) {
        float mx = -1e30f;
#pragma unroll
        for (int j = 0; j < NR; ++j) mx = fmaxf(mx, acc[i][j][r] + bvj[j]);
        mx = fmaxf(mx, __shfl_xor(mx, 1));
        mx = fmaxf(mx, __shfl_xor(mx, 2));
        mx = fmaxf(mx, __shfl_xor(mx, 4));
        mx = fmaxf(mx, __shfl_xor(mx, 8));
        float sum = 0.f;
#pragma unroll
        for (int j = 0; j < NR; ++j) sum += __expf(acc[i][j][r] + bvj[j] - mx);
        sum += __shfl_xor(sum, 1); sum += __shfl_xor(sum, 2);
        sum += __shfl_xor(sum, 4); sum += __shfl_xor(sum, 8);
        if (llo == 0) {
          int lr = wm + i * 16 + lhi * 4 + r;
          lbm[lr * 4 + (wn >> 6)] = mx;
          lbs[lr * 4 + (wn >> 6)] = sum;
        }
      }
    }
    __syncthreads();
    if (tid < 256) {
      float m = lbm[tid * 4], ss;
      m = fmaxf(fmaxf(m, lbm[tid * 4 + 1]), fmaxf(lbm[tid * 4 + 2], lbm[tid * 4 + 3]));
      ss = lbs[tid * 4 + 0] * __expf(lbm[tid * 4 + 0] - m)
         + lbs[tid * 4 + 1] * __expf(lbm[tid * 4 + 1] - m)
         + lbs[tid * 4 + 2] * __expf(lbm[tid * 4 + 2] - m)
         + lbs[tid * 4 + 3] * __expf(lbm[tid * 4 + 3] - m);
      int nt = N >> 8;
      pmax[(size_t)(m0 + tid) * nt + by] = m;
      psum[(size_t)(m0 + tid) * nt + by] = ss;
    }
  }
}

// -------- fused attention, one (b,h) per block, T=256, hd=64, strided QKV ----
__global__ __launch_bounds__(256) void attn_kernel(
    const u16* __restrict__ Qp, int qs, const u16* __restrict__ Kp,
    const u16* __restrict__ Vp, int kvs, u16* __restrict__ Ob, int causal) {
  __shared__ __align__(16) u16 Ks[256][72];
  __shared__ __align__(16) u16 Vt[64][264];
  __shared__ __align__(16) u16 Ps[4][16][264];
  const int tid = threadIdx.x, lane = tid & 63, w = tid >> 6;
  const int b = blockIdx.x >> 3, h = blockIdx.x & 7;
  const size_t qbase  = (size_t)b * 256 * qs  + (size_t)h * 64;
  const size_t kvbase = (size_t)b * 256 * kvs + (size_t)h * 64;
  const size_t obase  = (size_t)b * 256 * 512 + (size_t)h * 64;
  {
    int t0 = tid >> 3, d0 = (tid & 7) * 8;
#pragma unroll
    for (int it = 0; it < 8; ++it) {
      int t = it * 32 + t0;
      s8v kv = *(const s8v*)(Kp + kvbase + (size_t)t * kvs + d0);
      *(s8v*)&Ks[t][d0] = kv;
      s8v vv = *(const s8v*)(Vp + kvbase + (size_t)t * kvs + d0);
#pragma unroll
      for (int j = 0; j < 8; ++j) Vt[d0 + j][t] = (u16)vv[j];
    }
  }
  __syncthreads();
  const int lhi = lane >> 4, llo = lane & 15;
  for (int qc = 0; qc < 4; ++qc) {
    const int qr0 = w * 64 + qc * 16;
    s8v aq0 = *(const s8v*)(Qp + qbase + (size_t)(qr0 + llo) * qs + lhi * 8);
    s8v aq1 = *(const s8v*)(Qp + qbase + (size_t)(qr0 + llo) * qs + 32 + lhi * 8);
    f4v S[16];
#pragma unroll
    for (int c = 0; c < 16; ++c) {
      s8v bk0 = *(const s8v*)&Ks[c * 16 + llo][lhi * 8];
      s8v bk1 = *(const s8v*)&Ks[c * 16 + llo][32 + lhi * 8];
      f4v z = {0.f, 0.f, 0.f, 0.f};
      z = __builtin_amdgcn_mfma_f32_16x16x32_bf16(aq0, bk0, z, 0, 0, 0);
      S[c] = __builtin_amdgcn_mfma_f32_16x16x32_bf16(aq1, bk1, z, 0, 0, 0);
    }
#pragma unroll
    for (int r = 0; r < 4; ++r) {
      const int tq = qr0 + lhi * 4 + r;
      float mx = -1e30f;
#pragma unroll
      for (int c = 0; c < 16; ++c) {
        float s = S[c][r] * 0.125f;
        if (causal && (c * 16 + llo) > tq) s = -1e30f;
        S[c][r] = s;
        mx = fmaxf(mx, s);
      }
      mx = fmaxf(mx, __shfl_xor(mx, 1));
      mx = fmaxf(mx, __shfl_xor(mx, 2));
      mx = fmaxf(mx, __shfl_xor(mx, 4));
      mx = fmaxf(mx, __shfl_xor(mx, 8));
      float sum = 0.f;
#pragma unroll
      for (int c = 0; c < 16; ++c) { float p = __expf(S[c][r] - mx); S[c][r] = p; sum += p; }
      sum += __shfl_xor(sum, 1); sum += __shfl_xor(sum, 2);
      sum += __shfl_xor(sum, 4); sum += __shfl_xor(sum, 8);
      float inv = 1.f / sum;
#pragma unroll
      for (int c = 0; c < 16; ++c)
        Ps[w][lhi * 4 + r][c * 16 + llo] = f2bf(S[c][r] * inv);
    }
    asm volatile("s_waitcnt lgkmcnt(0)" ::: "memory");
    f4v o[4] = {};
#pragma unroll
    for (int kb = 0; kb < 8; ++kb) {
      s8v pa = *(const s8v*)&Ps[w][llo][kb * 32 + lhi * 8];
#pragma unroll
      for (int nb = 0; nb < 4; ++nb) {
        s8v bv = *(const s8v*)&Vt[nb * 16 + llo][kb * 32 + lhi * 8];
        o[nb] = __builtin_amdgcn_mfma_f32_16x16x32_bf16(pa, bv, o[nb], 0, 0, 0);
      }
    }
#pragma unroll
    for (int nb = 0; nb < 4; ++nb)
#pragma unroll
      for (int r = 0; r < 4; ++r)
        Ob[obase + (size_t)(qr0 + lhi * 4 + r) * 512 + nb * 16 + llo] = f2bf(o[nb][r]);
  }
}

// ---------------- loss: merge per-tile partials -> per-row nll ----------------
__global__ __launch_bounds__(256) void loss_lse_kernel(const float* __restrict__ pmax,
    const float* __restrict__ psum, const float* __restrict__ logits,
    const int* __restrict__ tgt, float* __restrict__ nll, float* __restrict__ valid) {
  const int w = threadIdx.x >> 6, lane = threadIdx.x & 63;
  const int row = blockIdx.x * 4 + w;
  float m = -1e30f, s = 0.f;
  for (int e = lane; e < 125; e += 64) {
    float pm = pmax[(size_t)row * 125 + e], ps = psum[(size_t)row * 125 + e];
    if (pm > m) { s = s * __expf(m - pm) + ps; m = pm; }
    else          s += ps * __expf(pm - m);
  }
#pragma unroll
  for (int o = 1; o < 64; o <<= 1) {
    float om = __shfl_xor(m, o), os = __shfl_xor(s, o);
    float mm = fmaxf(m, om);
    s = s * __expf(m - mm) + os * __expf(om - mm);
    m = mm;
  }
  if (lane == 0) {
    int t = tgt[row];
    float lse = m + logf(s);
    float v = (t != 1) ? 1.f : 0.f;
    nll[row] = v * (lse - logits[(size_t)row * 32000 + t]);
    valid[row] = v;
  }
}

__global__ __launch_bounds__(256) void loss_final_kernel(const float* __restrict__ nll,
    const float* __restrict__ valid, float* __restrict__ out) {
  __shared__ float sa[256], sb[256];
  int tid = threadIdx.x;
  float s = 0.f, c = 0.f;
  for (int i = tid; i < 16384; i += 256) { s += nll[i]; c += valid[i]; }
  sa[tid] = s; sb[tid] = c;
  __syncthreads();
  for (int st = 128; st > 0; st >>= 1) {
    if (tid < st) { sa[tid] += sa[tid + st]; sb[tid] += sb[tid + st]; }
    __syncthreads();
  }
  if (tid == 0) out[0] = sa[0] / fmaxf(sb[0], 1.f);
}

// =============================== host ===============================
extern "C" void kernel_launch(void* const* d_in, const int* in_sizes, int n_in,
                              void* d_out, int out_size, void* d_ws, size_t ws_size,
                              hipStream_t stream) {
  (void)in_sizes; (void)n_in; (void)out_size; (void)ws_size;
  const int* idx       = (const int*)d_in[0];
  const int* idx_enc   = (const int*)d_in[1];
  const int* targets   = (const int*)d_in[2];
  const float* emb_dec = (const float*)d_in[3];
  const float* emb_enc = (const float*)d_in[4];
  const float* enc_Wq  = (const float*)d_in[5];
  const float* enc_Wk  = (const float*)d_in[6];
  const float* enc_Wv  = (const float*)d_in[7];
  const float* enc_Wo  = (const float*)d_in[8];
  const float* enc_bo  = (const float*)d_in[9];
  const float* enc_ln_g = (const float*)d_in[10];
  const float* enc_ln_b = (const float*)d_in[11];
  const float* enc_W1  = (const float*)d_in[12];
  const float* enc_b1  = (const float*)d_in[13];
  const float* enc_W2  = (const float*)d_in[14];
  const float* enc_b2  = (const float*)d_in[15];
  const float* dWq_sa  = (const float*)d_in[16];
  const float* dWk_sa  = (const float*)d_in[17];
  const float* dWv_sa  = (const float*)d_in[18];
  const float* dWo_sa  = (const float*)d_in[19];
  const float* dbo_sa  = (const float*)d_in[20];
  const float* dWq_xa  = (const float*)d_in[21];
  const float* dWk_xa  = (const float*)d_in[22];
  const float* dWv_xa  = (const float*)d_in[23];
  const float* dWo_xa  = (const float*)d_in[24];
  const float* dbo_xa  = (const float*)d_in[25];
  const float* dec_ln_g = (const float*)d_in[26];
  const float* dec_ln_b = (const float*)d_in[27];
  const float* dec_W1  = (const float*)d_in[28];
  const float* dec_b1  = (const float*)d_in[29];
  const float* dec_W2  = (const float*)d_in[30];
  const float* dec_b2  = (const float*)d_in[31];
  const float* lnf_g   = (const float*)d_in[32];
  const float* lnf_b   = (const float*)d_in[33];
  const float* Wlm     = (const float*)d_in[34];
  const float* blm     = (const float*)d_in[35];
  float* out_logits = (float*)d_out;
  float* out_loss   = out_logits + (size_t)16384 * 32000;

  size_t off = 0;
  auto alloc = [&](size_t bytes) -> char* {
    char* p = (char*)d_ws + off;
    off += (bytes + 255) & ~(size_t)255;
    return p;
  };
  const size_t SQ = 512 * 512, SF = 512 * 2048;
  u16* tWqkvE = (u16*)alloc(6 * 3 * SQ * 2);
  u16* tWoE   = (u16*)alloc(6 * SQ * 2);
  u16* tW1E   = (u16*)alloc(6 * SF * 2);
  u16* tW2E   = (u16*)alloc(6 * SF * 2);
  u16* tWqkvS = (u16*)alloc(6 * 3 * SQ * 2);
  u16* tWoS   = (u16*)alloc(6 * SQ * 2);
  u16* tWqX   = (u16*)alloc(6 * SQ * 2);
  u16* tWkvX  = (u16*)alloc(6 * 2 * SQ * 2);
  u16* tWoX   = (u16*)alloc(6 * SQ * 2);
  u16* tW1D   = (u16*)alloc(6 * SF * 2);
  u16* tW2D   = (u16*)alloc(6 * SF * 2);
  u16* tWlm   = (u16*)alloc((size_t)32000 * 512 * 2);
  float* pe   = (float*)alloc(256 * 512 * 4);
  float* yE   = (float*)alloc((size_t)16384 * 512 * 4);
  float* xD   = (float*)alloc((size_t)16384 * 512 * 4);
  u16* hA     = (u16*)alloc((size_t)16384 * 512 * 2);
  u16* hB     = (u16*)alloc((size_t)16384 * 512 * 2);
  u16* qkvB   = (u16*)alloc((size_t)16384 * 1536 * 2);
  u16* qB     = (u16*)alloc((size_t)16384 * 512 * 2);
  u16* kvB    = (u16*)alloc((size_t)16384 * 1024 * 2);
  u16* atB    = (u16*)alloc((size_t)16384 * 512 * 2);
  u16* midB   = (u16*)alloc((size_t)16384 * 2048 * 2);
  float* pmax = (float*)alloc((size_t)16384 * 125 * 4);
  float* psum = (float*)alloc((size_t)16384 * 125 * 4);
  float* rnll = (float*)alloc(16384 * 4);
  float* rval = (float*)alloc(16384 * 4);

  // ---- weight conversion (every call; deterministic) ----
  dim3 tb(256);
  const size_t S3 = 3 * SQ, S2 = 2 * SQ;
  wconv_kernel<<<dim3(8, 8, 6), tb, 0, stream>>>(enc_Wq, tWqkvE + 0 * SQ, 512, 512, S3);
  wconv_kernel<<<dim3(8, 8, 6), tb, 0, stream>>>(enc_Wk, tWqkvE + 1 * SQ, 512, 512, S3);
  wconv_kernel<<<dim3(8, 8, 6), tb, 0, stream>>>(enc_Wv, tWqkvE + 2 * SQ, 512, 512, S3);
  wconv_kernel<<<dim3(8, 8, 6), tb, 0, stream>>>(enc_Wo, tWoE, 512, 512, SQ);
  wconv_kernel<<<dim3(8, 32, 6), tb, 0, stream>>>(enc_W1, tW1E, 512, 2048, SF);
  wconv_kernel<<<dim3(32, 8, 6), tb, 0, stream>>>(enc_W2, tW2E, 2048, 512, SF);
  wconv_kernel<<<dim3(8, 8, 6), tb, 0, stream>>>(dWq_sa, tWqkvS + 0 * SQ, 512, 512, S3);
  wconv_kernel<<<dim3(8, 8, 6), tb, 0, stream>>>(dWk_sa, tWqkvS + 1 * SQ, 512, 512, S3);
  wconv_kernel<<<dim3(8, 8, 6), tb, 0, stream>>>(dWv_sa, tWqkvS + 2 * SQ, 512, 512, S3);
  wconv_kernel<<<dim3(8, 8, 6), tb, 0, stream>>>(dWo_sa, tWoS, 512, 512, SQ);
  wconv_kernel<<<dim3(8, 8, 6), tb, 0, stream>>>(dWq_xa, tWqX, 512, 512, SQ);
  wconv_kernel<<<dim3(8, 8, 6), tb, 0, stream>>>(dWk_xa, tWkvX + 0 * SQ, 512, 512, S2);
  wconv_kernel<<<dim3(8, 8, 6), tb, 0, stream>>>(dWv_xa, tWkvX + 1 * SQ, 512, 512, S2);
  wconv_kernel<<<dim3(8, 8, 6), tb, 0, stream>>>(dWo_xa, tWoX, 512, 512, SQ);
  wconv_kernel<<<dim3(8, 32, 6), tb, 0, stream>>>(dec_W1, tW1D, 512, 2048, SF);
  wconv_kernel<<<dim3(32, 8, 6), tb, 0, stream>>>(dec_W2, tW2D, 2048, 512, SF);
  wconv_kernel<<<dim3(8, 500, 1), tb, 0, stream>>>(Wlm, tWlm, 512, 32000, (size_t)0);
  pe_kernel<<<256, 256, 0, stream>>>(pe);

  auto ln = [&](const float* xin, const float* g, const float* bb, u16* o) {
    ln_kernel<<<4096, 256, 0, stream>>>(xin, g, bb, o);
  };
  // N >= 1024: BN=256 kernel; N == 512: BN=128 kernel (grid stays >= 256 blocks)
  auto g_bf16_4 = [&](const u16* Ap, const u16* Bp, u16* Op, int N) {
    gemm256_kernel<4, 0, 0, 0, 1, 0><<<dim3(64, N / 256), 512, 0, stream>>>(
        Ap, Bp, nullptr, nullptr, Op, 16384, N, 512, nullptr, nullptr);
  };
  auto g_bf16_2 = [&](const u16* Ap, const u16* Bp, u16* Op) {
    gemm256_kernel<2, 0, 0, 0, 1, 0><<<dim3(64, 4), 512, 0, stream>>>(
        Ap, Bp, nullptr, nullptr, Op, 16384, 512, 512, nullptr, nullptr);
  };
  auto proj_res = [&](const u16* Ap, const u16* Bp, const float* bi, float* xr, int K) {
    gemm256_kernel<2, 1, 1, 0, 0, 0><<<dim3(64, 4), 512, 0, stream>>>(
        Ap, Bp, bi, xr, xr, 16384, 512, K, nullptr, nullptr);
  };
  auto ffn1 = [&](const u16* Ap, const u16* Bp, const float* bi, u16* Op) {
    gemm256_kernel<4, 1, 0, 1, 1, 0><<<dim3(64, 8), 512, 0, stream>>>(
        Ap, Bp, bi, nullptr, Op, 16384, 2048, 512, nullptr, nullptr);
  };

  // ---------------- encoder ----------------
  embed_kernel<<<8192, 256, 0, stream>>>(idx_enc, emb_enc, pe, yE);
  for (int l = 0; l < 6; ++l) {
    ln(yE, enc_ln_g + (l * 2 + 0) * 512, enc_ln_b + (l * 2 + 0) * 512, hA);
    g_bf16_4(hA, tWqkvE + l * S3, qkvB, 1536);
    attn_kernel<<<512, 256, 0, stream>>>(qkvB, 1536, qkvB + 512, qkvB + 1024, 1536, atB, 0);
    proj_res(atB, tWoE + l * SQ, enc_bo + l * 512, yE, 512);
    ln(yE, enc_ln_g + (l * 2 + 1) * 512, enc_ln_b + (l * 2 + 1) * 512, hA);
    ffn1(hA, tW1E + l * SF, enc_b1 + l * 2048, midB);
    proj_res(midB, tW2E + l * SF, enc_b2 + l * 512, yE, 2048);
  }

  // ---------------- decoder ----------------
  embed_kernel<<<8192, 256, 0, stream>>>(idx, emb_dec, pe, xD);
  for (int l = 0; l < 6; ++l) {
    ln(xD, dec_ln_g + (l * 4 + 0) * 512, dec_ln_b + (l * 4 + 0) * 512, hA);
    g_bf16_4(hA, tWqkvS + l * S3, qkvB, 1536);
    attn_kernel<<<512, 256, 0, stream>>>(qkvB, 1536, qkvB + 512, qkvB + 1024, 1536, atB, 1);
    proj_res(atB, tWoS + l * SQ, dbo_sa + l * 512, xD, 512);
    ln(xD, dec_ln_g + (l * 4 + 1) * 512, dec_ln_b + (l * 4 + 1) * 512, hA);
    ln(yE, dec_ln_g + (l * 4 + 2) * 512, dec_ln_b + (l * 4 + 2) * 512, hB);
    g_bf16_2(hA, tWqX + l * SQ, qB);
    g_bf16_4(hB, tWkvX + l * S2, kvB, 1024);
    attn_kernel<<<512, 256, 0, stream>>>(qB, 512, kvB, kvB + 512, 1024, atB, 0);
    proj_res(atB, tWoX + l * SQ, dbo_xa + l * 512, xD, 512);
    ln(xD, dec_ln_g + (l * 4 + 3) * 512, dec_ln_b + (l * 4 + 3) * 512, hA);
    ffn1(hA, tW1D + l * SF, dec_b1 + l * 2048, midB);
    proj_res(midB, tW2D + l * SF, dec_b2 + l * 512, xD, 2048);
  }

  // ---------------- LM head (fused loss partials) + loss ----------------
  ln(xD, lnf_g, lnf_b, hA);
  gemm256_kernel<4, 1, 0, 0, 0, 1><<<dim3(64, 125), 512, 0, stream>>>(
      hA, tWlm, blm, nullptr, out_logits, 16384, 32000, 512, pmax, psum);
  loss_lse_kernel<<<4096, 256, 0, stream>>>(pmax, psum, out_logits, targets, rnll, rval);
  loss_final_kernel<<<1, 256, 0, stream>>>(rnll, rval, out_loss);
}

// Round 4
// 5433.933 us; speedup vs baseline: 1.1296x; 1.0578x over previous
//
#include <hip/hip_runtime.h>

typedef __attribute__((ext_vector_type(8))) short s8v;
typedef __attribute__((ext_vector_type(4))) float f4v;
using u16 = unsigned short;

__device__ __forceinline__ u16 f2bf(float f) {
  union { float f; unsigned u; } v; v.f = f;
  return (u16)((v.u + 0x7FFFu + ((v.u >> 16) & 1u)) >> 16);
}

// ---------------- positional encoding: pe[256][512] ----------------
__global__ __launch_bounds__(256) void pe_kernel(float* __restrict__ pe) {
  int i = blockIdx.x * 256 + threadIdx.x;
  int t = i >> 8, p = i & 255;
  float ex = (2.f * (float)p) / 512.f;
  float ang = (float)t * expf(-ex * 9.210340371976184f);
  pe[t * 512 + 2 * p]     = sinf(ang);
  pe[t * 512 + 2 * p + 1] = cosf(ang);
}

// -------- weight convert: f32 [R][C] -> bf16 [C][R], z-batched, dst stride --
__global__ __launch_bounds__(256) void wconv_kernel(const float* __restrict__ in,
    u16* __restrict__ out, int R, int C, size_t dstride) {
  __shared__ float tile[64][65];
  const size_t mat = (size_t)R * C;
  const float* src = in + (size_t)blockIdx.z * mat;
  u16* dst = out + (size_t)blockIdx.z * dstride;
  int r0 = blockIdx.x * 64, c0 = blockIdx.y * 64;
  int tr = threadIdx.x >> 6, tc = threadIdx.x & 63;
#pragma unroll
  for (int i = 0; i < 16; ++i)
    tile[i * 4 + tr][tc] = src[(size_t)(r0 + i * 4 + tr) * C + (c0 + tc)];
  __syncthreads();
#pragma unroll
  for (int i = 0; i < 16; ++i)
    dst[(size_t)(c0 + i * 4 + tr) * R + (r0 + tc)] = f2bf(tile[tc][i * 4 + tr]);
}

// ---------------- embedding + pe ----------------
__global__ __launch_bounds__(256) void embed_kernel(const int* __restrict__ idx,
    const float* __restrict__ emb, const float* __restrict__ pe, float* __restrict__ y) {
  int i = blockIdx.x * 256 + threadIdx.x;
  int row = i >> 7, c = (i & 127) * 4;
  int t = row & 255;
  int tok = idx[row];
  f4v e = *(const f4v*)(emb + (size_t)tok * 512 + c);
  f4v p = *(const f4v*)(pe + (size_t)t * 512 + c);
  *(f4v*)(y + (size_t)row * 512 + c) = e + p;
}

// ---------------- LayerNorm f32 -> bf16, wave per row ----------------
__global__ __launch_bounds__(256) void ln_kernel(const float* __restrict__ x,
    const float* __restrict__ g, const float* __restrict__ b, u16* __restrict__ out) {
  int row = blockIdx.x * 4 + (threadIdx.x >> 6);
  int lane = threadIdx.x & 63;
  const float* xr = x + (size_t)row * 512 + lane * 8;
  f4v v0 = *(const f4v*)xr;
  f4v v1 = *(const f4v*)(xr + 4);
  float s = v0[0] + v0[1] + v0[2] + v0[3] + v1[0] + v1[1] + v1[2] + v1[3];
#pragma unroll
  for (int o = 1; o < 64; o <<= 1) s += __shfl_xor(s, o);
  float mu = s * (1.f / 512.f);
  float q = 0.f;
#pragma unroll
  for (int j = 0; j < 4; ++j) {
    float d0 = v0[j] - mu; q += d0 * d0;
    float d1 = v1[j] - mu; q += d1 * d1;
  }
#pragma unroll
  for (int o = 1; o < 64; o <<= 1) q += __shfl_xor(q, o);
  float rs = rsqrtf(q * (1.f / 512.f) + 1e-5f);
  f4v g0 = *(const f4v*)(g + lane * 8), g1 = *(const f4v*)(g + lane * 8 + 4);
  f4v b0 = *(const f4v*)(b + lane * 8), b1 = *(const f4v*)(b + lane * 8 + 4);
  s8v ov;
#pragma unroll
  for (int j = 0; j < 4; ++j) {
    ov[j]     = (short)f2bf((v0[j] - mu) * rs * g0[j] + b0[j]);
    ov[4 + j] = (short)f2bf((v1[j] - mu) * rs * g1[j] + b1[j]);
  }
  *(s8v*)(out + (size_t)row * 512 + lane * 8) = ov;
}

// ======== GEMM: C[M,N] = A[M,K](bf16) @ Bt[N,K](bf16)^T ========
// 256xBN tile (BN = NR*64), BK=64, 8 waves (2M x 4N), double-buffered LDS,
// 2-phase pipeline + T2 XOR swizzle (linear LDS dest, pre-swizzled global
// source slot; ds_read applies same XOR). Involution: LDS[r][s]=G[s^(r&7)].
template<int NR, int HAS_BIAS, int ADD_RES, int RELU, int OUT_BF16, int WLOSS>
__global__ __launch_bounds__(512, 2) void gemm256_kernel(
    const u16* __restrict__ A, const u16* __restrict__ Bt,
    const float* __restrict__ bias, const float* __restrict__ res,
    void* __restrict__ outp, int M, int N, int K,
    float* __restrict__ pmax, float* __restrict__ psum) {
  __shared__ __align__(16) u16 As[2][256 * 64];
  __shared__ __align__(16) u16 Bs[2][NR * 64 * 64];
  const int tid = threadIdx.x, lane = tid & 63, w = tid >> 6;
  // bijective XCD swizzle (grid always % 8 == 0 here)
  int nx = gridDim.x;
  int flat = blockIdx.y * nx + blockIdx.x;
  int per = (nx * gridDim.y) >> 3;
  int s = (flat & 7) * per + (flat >> 3);
  int by = s / nx, bx = s - by * nx;
  const int m0 = bx * 256, n0 = by * (NR * 64);
  const int wm = (w >> 2) * 128, wn = (w & 3) * (NR * 16);
  const int lhi = lane >> 4, llo = lane & 15;
  const int srow = tid >> 3;
  const int sl = tid & 7;                         // 16B slot within 128B row
  const int gcol = ((sl ^ (srow & 7)) * 8);       // pre-swizzled global slot

  const u16* Ag = A + (size_t)(m0 + srow) * K + gcol;
  const u16* Bg = Bt + (size_t)(n0 + srow) * K + gcol;
  const size_t rstep = (size_t)64 * K;

  auto STAGE = [&](int b, int kt) {
#pragma unroll
    for (int q = 0; q < 4; ++q)
      __builtin_amdgcn_global_load_lds(
          (const __attribute__((address_space(1))) void*)(Ag + q * rstep + kt),
          (__attribute__((address_space(3))) void*)(&As[b][(q * 64 + srow) * 64 + sl * 8]),
          16, 0, 0);
#pragma unroll
    for (int q = 0; q < NR; ++q)
      __builtin_amdgcn_global_load_lds(
          (const __attribute__((address_space(1))) void*)(Bg + q * rstep + kt),
          (__attribute__((address_space(3))) void*)(&Bs[b][(q * 64 + srow) * 64 + sl * 8]),
          16, 0, 0);
  };
  // swizzled read offset within a 64-elem row, for fragment (kk, lhi), row r:
  //   slot = (kk*4 + lhi) ^ (r & 7); element = slot*8. Here r&7 == llo&7.
  const int sx = llo & 7;

  f4v acc[8][NR] = {};
  const int nk = K >> 6;
  STAGE(0, 0);
  asm volatile("s_waitcnt vmcnt(0)" ::: "memory");
  __builtin_amdgcn_s_barrier();
  __builtin_amdgcn_sched_barrier(0);
  int cur = 0;
  for (int t = 0; t < nk; ++t) {
    if (t + 1 < nk) STAGE(cur ^ 1, (t + 1) * 64);
#pragma unroll
    for (int kk = 0; kk < 2; ++kk) {
      s8v af[8], bfv[NR];
#pragma unroll
      for (int i = 0; i < 8; ++i)
        af[i] = *(const s8v*)&As[cur][(wm + i * 16 + llo) * 64 + (((kk * 4 + lhi) ^ sx) * 8)];
#pragma unroll
      for (int j = 0; j < NR; ++j)
        bfv[j] = *(const s8v*)&Bs[cur][(wn + j * 16 + llo) * 64 + (((kk * 4 + lhi) ^ sx) * 8)];
      __builtin_amdgcn_s_setprio(1);
#pragma unroll
      for (int i = 0; i < 8; ++i)
#pragma unroll
        for (int j = 0; j < NR; ++j)
          acc[i][j] = __builtin_amdgcn_mfma_f32_16x16x32_bf16(af[i], bfv[j], acc[i][j], 0, 0, 0);
      __builtin_amdgcn_s_setprio(0);
    }
    asm volatile("s_waitcnt vmcnt(0)" ::: "memory");
    __builtin_amdgcn_s_barrier();
    __builtin_amdgcn_sched_barrier(0);
    cur ^= 1;
  }
  // epilogue: D row = (l>>4)*4 + r, col = l&15 (verified layout)
  float bvj[NR];
#pragma unroll
  for (int j = 0; j < NR; ++j)
    bvj[j] = HAS_BIAS ? bias[n0 + wn + j * 16 + llo] : 0.f;
#pragma unroll
  for (int i = 0; i < 8; ++i) {
#pragma unroll
    for (int j = 0; j < NR; ++j) {
      int col = n0 + wn + j * 16 + llo;
#pragma unroll
      for (int r = 0; r < 4; ++r) {
        int row = m0 + wm + i * 16 + lhi * 4 + r;
        float v = acc[i][j][r] + bvj[j];
        if (ADD_RES) v += res[(size_t)row * N + col];
        if (RELU) v = fmaxf(v, 0.f);
        if (OUT_BF16) ((u16*)outp)[(size_t)row * N + col] = f2bf(v);
        else          ((float*)outp)[(size_t)row * N + col] = v;
      }
    }
  }
  if (WLOSS && NR == 4) {
    float* lbm = (float*)&As[0][0];        // 256 rows x 4 wave-cols
    float* lbs = lbm + 1024;
#pragma unroll
    for (int i = 0; i < 8; ++i) {
#pragma unroll
      for (int r = 0; r < 4; ++r) {
        float mx = -1e30f;
#pragma unroll
        for (int j = 0; j < NR; ++j) mx = fmaxf(mx, acc[i][j][r] + bvj[j]);
        mx = fmaxf(mx, __shfl_xor(mx, 1));
        mx = fmaxf(mx, __shfl_xor(mx, 2));
        mx = fmaxf(mx, __shfl_xor(mx, 4));
        mx = fmaxf(mx, __shfl_xor(mx, 8));
        float sum = 0.f;
#pragma unroll
        for (int j = 0; j < NR; ++j) sum += __expf(acc[i][j][r] + bvj[j] - mx);
        sum += __shfl_xor(sum, 1); sum += __shfl_xor(sum, 2);
        sum += __shfl_xor(sum, 4); sum += __shfl_xor(sum, 8);
        if (llo == 0) {
          int lr = wm + i * 16 + lhi * 4 + r;
          lbm[lr * 4 + (wn >> 6)] = mx;
          lbs[lr * 4 + (wn >> 6)] = sum;
        }
      }
    }
    __syncthreads();
    if (tid < 256) {
      float m = lbm[tid * 4], ss;
      m = fmaxf(fmaxf(m, lbm[tid * 4 + 1]), fmaxf(lbm[tid * 4 + 2], lbm[tid * 4 + 3]));
      ss = lbs[tid * 4 + 0] * __expf(lbm[tid * 4 + 0] - m)
         + lbs[tid * 4 + 1] * __expf(lbm[tid * 4 + 1] - m)
         + lbs[tid * 4 + 2] * __expf(lbm[tid * 4 + 2] - m)
         + lbs[tid * 4 + 3] * __expf(lbm[tid * 4 + 3] - m);
      int nt = N >> 8;
      pmax[(size_t)(m0 + tid) * nt + by] = m;
      psum[(size_t)(m0 + tid) * nt + by] = ss;
    }
  }
}

// -------- fused attention, one (b,h) per block, T=256, hd=64, strided QKV ----
__global__ __launch_bounds__(256) void attn_kernel(
    const u16* __restrict__ Qp, int qs, const u16* __restrict__ Kp,
    const u16* __restrict__ Vp, int kvs, u16* __restrict__ Ob, int causal) {
  __shared__ __align__(16) u16 Ks[256][72];
  __shared__ __align__(16) u16 Vt[64][264];
  __shared__ __align__(16) u16 Ps[4][16][264];
  const int tid = threadIdx.x, lane = tid & 63, w = tid >> 6;
  const int b = blockIdx.x >> 3, h = blockIdx.x & 7;
  const size_t qbase  = (size_t)b * 256 * qs  + (size_t)h * 64;
  const size_t kvbase = (size_t)b * 256 * kvs + (size_t)h * 64;
  const size_t obase  = (size_t)b * 256 * 512 + (size_t)h * 64;
  {
    int t0 = tid >> 3, d0 = (tid & 7) * 8;
#pragma unroll
    for (int it = 0; it < 8; ++it) {
      int t = it * 32 + t0;
      s8v kv = *(const s8v*)(Kp + kvbase + (size_t)t * kvs + d0);
      *(s8v*)&Ks[t][d0] = kv;
      s8v vv = *(const s8v*)(Vp + kvbase + (size_t)t * kvs + d0);
#pragma unroll
      for (int j = 0; j < 8; ++j) Vt[d0 + j][t] = (u16)vv[j];
    }
  }
  __syncthreads();
  const int lhi = lane >> 4, llo = lane & 15;
  for (int qc = 0; qc < 4; ++qc) {
    const int qr0 = w * 64 + qc * 16;
    s8v aq0 = *(const s8v*)(Qp + qbase + (size_t)(qr0 + llo) * qs + lhi * 8);
    s8v aq1 = *(const s8v*)(Qp + qbase + (size_t)(qr0 + llo) * qs + 32 + lhi * 8);
    f4v S[16];
#pragma unroll
    for (int c = 0; c < 16; ++c) {
      s8v bk0 = *(const s8v*)&Ks[c * 16 + llo][lhi * 8];
      s8v bk1 = *(const s8v*)&Ks[c * 16 + llo][32 + lhi * 8];
      f4v z = {0.f, 0.f, 0.f, 0.f};
      z = __builtin_amdgcn_mfma_f32_16x16x32_bf16(aq0, bk0, z, 0, 0, 0);
      S[c] = __builtin_amdgcn_mfma_f32_16x16x32_bf16(aq1, bk1, z, 0, 0, 0);
    }
#pragma unroll
    for (int r = 0; r < 4; ++r) {
      const int tq = qr0 + lhi * 4 + r;
      float mx = -1e30f;
#pragma unroll
      for (int c = 0; c < 16; ++c) {
        float s = S[c][r] * 0.125f;
        if (causal && (c * 16 + llo) > tq) s = -1e30f;
        S[c][r] = s;
        mx = fmaxf(mx, s);
      }
      mx = fmaxf(mx, __shfl_xor(mx, 1));
      mx = fmaxf(mx, __shfl_xor(mx, 2));
      mx = fmaxf(mx, __shfl_xor(mx, 4));
      mx = fmaxf(mx, __shfl_xor(mx, 8));
      float sum = 0.f;
#pragma unroll
      for (int c = 0; c < 16; ++c) { float p = __expf(S[c][r] - mx); S[c][r] = p; sum += p; }
      sum += __shfl_xor(sum, 1); sum += __shfl_xor(sum, 2);
      sum += __shfl_xor(sum, 4); sum += __shfl_xor(sum, 8);
      float inv = 1.f / sum;
#pragma unroll
      for (int c = 0; c < 16; ++c)
        Ps[w][lhi * 4 + r][c * 16 + llo] = f2bf(S[c][r] * inv);
    }
    asm volatile("s_waitcnt lgkmcnt(0)" ::: "memory");
    f4v o[4] = {};
#pragma unroll
    for (int kb = 0; kb < 8; ++kb) {
      s8v pa = *(const s8v*)&Ps[w][llo][kb * 32 + lhi * 8];
#pragma unroll
      for (int nb = 0; nb < 4; ++nb) {
        s8v bv = *(const s8v*)&Vt[nb * 16 + llo][kb * 32 + lhi * 8];
        o[nb] = __builtin_amdgcn_mfma_f32_16x16x32_bf16(pa, bv, o[nb], 0, 0, 0);
      }
    }
#pragma unroll
    for (int nb = 0; nb < 4; ++nb)
#pragma unroll
      for (int r = 0; r < 4; ++r)
        Ob[obase + (size_t)(qr0 + lhi * 4 + r) * 512 + nb * 16 + llo] = f2bf(o[nb][r]);
  }
}

// ---------------- loss: merge per-tile partials -> per-row nll ----------------
__global__ __launch_bounds__(256) void loss_lse_kernel(const float* __restrict__ pmax,
    const float* __restrict__ psum, const float* __restrict__ logits,
    const int* __restrict__ tgt, float* __restrict__ nll, float* __restrict__ valid) {
  const int w = threadIdx.x >> 6, lane = threadIdx.x & 63;
  const int row = blockIdx.x * 4 + w;
  float m = -1e30f, s = 0.f;
  for (int e = lane; e < 125; e += 64) {
    float pm = pmax[(size_t)row * 125 + e], ps = psum[(size_t)row * 125 + e];
    if (pm > m) { s = s * __expf(m - pm) + ps; m = pm; }
    else          s += ps * __expf(pm - m);
  }
#pragma unroll
  for (int o = 1; o < 64; o <<= 1) {
    float om = __shfl_xor(m, o), os = __shfl_xor(s, o);
    float mm = fmaxf(m, om);
    s = s * __expf(m - mm) + os * __expf(om - mm);
    m = mm;
  }
  if (lane == 0) {
    int t = tgt[row];
    float lse = m + logf(s);
    float v = (t != 1) ? 1.f : 0.f;
    nll[row] = v * (lse - logits[(size_t)row * 32000 + t]);
    valid[row] = v;
  }
}

__global__ __launch_bounds__(256) void loss_final_kernel(const float* __restrict__ nll,
    const float* __restrict__ valid, float* __restrict__ out) {
  __shared__ float sa[256], sb[256];
  int tid = threadIdx.x;
  float s = 0.f, c = 0.f;
  for (int i = tid; i < 16384; i += 256) { s += nll[i]; c += valid[i]; }
  sa[tid] = s; sb[tid] = c;
  __syncthreads();
  for (int st = 128; st > 0; st >>= 1) {
    if (tid < st) { sa[tid] += sa[tid + st]; sb[tid] += sb[tid + st]; }
    __syncthreads();
  }
  if (tid == 0) out[0] = sa[0] / fmaxf(sb[0], 1.f);
}

// =============================== host ===============================
extern "C" void kernel_launch(void* const* d_in, const int* in_sizes, int n_in,
                              void* d_out, int out_size, void* d_ws, size_t ws_size,
                              hipStream_t stream) {
  (void)in_sizes; (void)n_in; (void)out_size; (void)ws_size;
  const int* idx       = (const int*)d_in[0];
  const int* idx_enc   = (const int*)d_in[1];
  const int* targets   = (const int*)d_in[2];
  const float* emb_dec = (const float*)d_in[3];
  const float* emb_enc = (const float*)d_in[4];
  const float* enc_Wq  = (const float*)d_in[5];
  const float* enc_Wk  = (const float*)d_in[6];
  const float* enc_Wv  = (const float*)d_in[7];
  const float* enc_Wo  = (const float*)d_in[8];
  const float* enc_bo  = (const float*)d_in[9];
  const float* enc_ln_g = (const float*)d_in[10];
  const float* enc_ln_b = (const float*)d_in[11];
  const float* enc_W1  = (const float*)d_in[12];
  const float* enc_b1  = (const float*)d_in[13];
  const float* enc_W2  = (const float*)d_in[14];
  const float* enc_b2  = (const float*)d_in[15];
  const float* dWq_sa  = (const float*)d_in[16];
  const float* dWk_sa  = (const float*)d_in[17];
  const float* dWv_sa  = (const float*)d_in[18];
  const float* dWo_sa  = (const float*)d_in[19];
  const float* dbo_sa  = (const float*)d_in[20];
  const float* dWq_xa  = (const float*)d_in[21];
  const float* dWk_xa  = (const float*)d_in[22];
  const float* dWv_xa  = (const float*)d_in[23];
  const float* dWo_xa  = (const float*)d_in[24];
  const float* dbo_xa  = (const float*)d_in[25];
  const float* dec_ln_g = (const float*)d_in[26];
  const float* dec_ln_b = (const float*)d_in[27];
  const float* dec_W1  = (const float*)d_in[28];
  const float* dec_b1  = (const float*)d_in[29];
  const float* dec_W2  = (const float*)d_in[30];
  const float* dec_b2  = (const float*)d_in[31];
  const float* lnf_g   = (const float*)d_in[32];
  const float* lnf_b   = (const float*)d_in[33];
  const float* Wlm     = (const float*)d_in[34];
  const float* blm     = (const float*)d_in[35];
  float* out_logits = (float*)d_out;
  float* out_loss   = out_logits + (size_t)16384 * 32000;

  size_t off = 0;
  auto alloc = [&](size_t bytes) -> char* {
    char* p = (char*)d_ws + off;
    off += (bytes + 255) & ~(size_t)255;
    return p;
  };
  const size_t SQ = 512 * 512, SF = 512 * 2048;
  u16* tWqkvE = (u16*)alloc(6 * 3 * SQ * 2);
  u16* tWoE   = (u16*)alloc(6 * SQ * 2);
  u16* tW1E   = (u16*)alloc(6 * SF * 2);
  u16* tW2E   = (u16*)alloc(6 * SF * 2);
  u16* tWqkvS = (u16*)alloc(6 * 3 * SQ * 2);
  u16* tWoS   = (u16*)alloc(6 * SQ * 2);
  u16* tWqX   = (u16*)alloc(6 * SQ * 2);
  u16* tWkvX  = (u16*)alloc(6 * 2 * SQ * 2);
  u16* tWoX   = (u16*)alloc(6 * SQ * 2);
  u16* tW1D   = (u16*)alloc(6 * SF * 2);
  u16* tW2D   = (u16*)alloc(6 * SF * 2);
  u16* tWlm   = (u16*)alloc((size_t)32000 * 512 * 2);
  float* pe   = (float*)alloc(256 * 512 * 4);
  float* yE   = (float*)alloc((size_t)16384 * 512 * 4);
  float* xD   = (float*)alloc((size_t)16384 * 512 * 4);
  u16* hA     = (u16*)alloc((size_t)16384 * 512 * 2);
  u16* hB     = (u16*)alloc((size_t)16384 * 512 * 2);
  u16* qkvB   = (u16*)alloc((size_t)16384 * 1536 * 2);
  u16* qB     = (u16*)alloc((size_t)16384 * 512 * 2);
  u16* kvB    = (u16*)alloc((size_t)16384 * 1024 * 2);
  u16* atB    = (u16*)alloc((size_t)16384 * 512 * 2);
  u16* midB   = (u16*)alloc((size_t)16384 * 2048 * 2);
  float* pmax = (float*)alloc((size_t)16384 * 125 * 4);
  float* psum = (float*)alloc((size_t)16384 * 125 * 4);
  float* rnll = (float*)alloc(16384 * 4);
  float* rval = (float*)alloc(16384 * 4);

  // ---- weight conversion (every call; deterministic) ----
  dim3 tb(256);
  const size_t S3 = 3 * SQ, S2 = 2 * SQ;
  wconv_kernel<<<dim3(8, 8, 6), tb, 0, stream>>>(enc_Wq, tWqkvE + 0 * SQ, 512, 512, S3);
  wconv_kernel<<<dim3(8, 8, 6), tb, 0, stream>>>(enc_Wk, tWqkvE + 1 * SQ, 512, 512, S3);
  wconv_kernel<<<dim3(8, 8, 6), tb, 0, stream>>>(enc_Wv, tWqkvE + 2 * SQ, 512, 512, S3);
  wconv_kernel<<<dim3(8, 8, 6), tb, 0, stream>>>(enc_Wo, tWoE, 512, 512, SQ);
  wconv_kernel<<<dim3(8, 32, 6), tb, 0, stream>>>(enc_W1, tW1E, 512, 2048, SF);
  wconv_kernel<<<dim3(32, 8, 6), tb, 0, stream>>>(enc_W2, tW2E, 2048, 512, SF);
  wconv_kernel<<<dim3(8, 8, 6), tb, 0, stream>>>(dWq_sa, tWqkvS + 0 * SQ, 512, 512, S3);
  wconv_kernel<<<dim3(8, 8, 6), tb, 0, stream>>>(dWk_sa, tWqkvS + 1 * SQ, 512, 512, S3);
  wconv_kernel<<<dim3(8, 8, 6), tb, 0, stream>>>(dWv_sa, tWqkvS + 2 * SQ, 512, 512, S3);
  wconv_kernel<<<dim3(8, 8, 6), tb, 0, stream>>>(dWo_sa, tWoS, 512, 512, SQ);
  wconv_kernel<<<dim3(8, 8, 6), tb, 0, stream>>>(dWq_xa, tWqX, 512, 512, SQ);
  wconv_kernel<<<dim3(8, 8, 6), tb, 0, stream>>>(dWk_xa, tWkvX + 0 * SQ, 512, 512, S2);
  wconv_kernel<<<dim3(8, 8, 6), tb, 0, stream>>>(dWv_xa, tWkvX + 1 * SQ, 512, 512, S2);
  wconv_kernel<<<dim3(8, 8, 6), tb, 0, stream>>>(dWo_xa, tWoX, 512, 512, SQ);
  wconv_kernel<<<dim3(8, 32, 6), tb, 0, stream>>>(dec_W1, tW1D, 512, 2048, SF);
  wconv_kernel<<<dim3(32, 8, 6), tb, 0, stream>>>(dec_W2, tW2D, 2048, 512, SF);
  wconv_kernel<<<dim3(8, 500, 1), tb, 0, stream>>>(Wlm, tWlm, 512, 32000, (size_t)0);
  pe_kernel<<<256, 256, 0, stream>>>(pe);

  auto ln = [&](const float* xin, const float* g, const float* bb, u16* o) {
    ln_kernel<<<4096, 256, 0, stream>>>(xin, g, bb, o);
  };
  auto g_bf16_4 = [&](const u16* Ap, const u16* Bp, u16* Op, int N) {
    gemm256_kernel<4, 0, 0, 0, 1, 0><<<dim3(64, N / 256), 512, 0, stream>>>(
        Ap, Bp, nullptr, nullptr, Op, 16384, N, 512, nullptr, nullptr);
  };
  auto g_bf16_2 = [&](const u16* Ap, const u16* Bp, u16* Op) {
    gemm256_kernel<2, 0, 0, 0, 1, 0><<<dim3(64, 4), 512, 0, stream>>>(
        Ap, Bp, nullptr, nullptr, Op, 16384, 512, 512, nullptr, nullptr);
  };
  auto proj_res = [&](const u16* Ap, const u16* Bp, const float* bi, float* xr, int K) {
    gemm256_kernel<2, 1, 1, 0, 0, 0><<<dim3(64, 4), 512, 0, stream>>>(
        Ap, Bp, bi, xr, xr, 16384, 512, K, nullptr, nullptr);
  };
  auto ffn1 = [&](const u16* Ap, const u16* Bp, const float* bi, u16* Op) {
    gemm256_kernel<4, 1, 0, 1, 1, 0><<<dim3(64, 8), 512, 0, stream>>>(
        Ap, Bp, bi, nullptr, Op, 16384, 2048, 512, nullptr, nullptr);
  };

  // ---------------- encoder ----------------
  embed_kernel<<<8192, 256, 0, stream>>>(idx_enc, emb_enc, pe, yE);
  for (int l = 0; l < 6; ++l) {
    ln(yE, enc_ln_g + (l * 2 + 0) * 512, enc_ln_b + (l * 2 + 0) * 512, hA);
    g_bf16_4(hA, tWqkvE + l * S3, qkvB, 1536);
    attn_kernel<<<512, 256, 0, stream>>>(qkvB, 1536, qkvB + 512, qkvB + 1024, 1536, atB, 0);
    proj_res(atB, tWoE + l * SQ, enc_bo + l * 512, yE, 512);
    ln(yE, enc_ln_g + (l * 2 + 1) * 512, enc_ln_b + (l * 2 + 1) * 512, hA);
    ffn1(hA, tW1E + l * SF, enc_b1 + l * 2048, midB);
    proj_res(midB, tW2E + l * SF, enc_b2 + l * 512, yE, 2048);
  }

  // ---------------- decoder ----------------
  embed_kernel<<<8192, 256, 0, stream>>>(idx, emb_dec, pe, xD);
  for (int l = 0; l < 6; ++l) {
    ln(xD, dec_ln_g + (l * 4 + 0) * 512, dec_ln_b + (l * 4 + 0) * 512, hA);
    g_bf16_4(hA, tWqkvS + l * S3, qkvB, 1536);
    attn_kernel<<<512, 256, 0, stream>>>(qkvB, 1536, qkvB + 512, qkvB + 1024, 1536, atB, 1);
    proj_res(atB, tWoS + l * SQ, dbo_sa + l * 512, xD, 512);
    ln(xD, dec_ln_g + (l * 4 + 1) * 512, dec_ln_b + (l * 4 + 1) * 512, hA);
    ln(yE, dec_ln_g + (l * 4 + 2) * 512, dec_ln_b + (l * 4 + 2) * 512, hB);
    g_bf16_2(hA, tWqX + l * SQ, qB);
    g_bf16_4(hB, tWkvX + l * S2, kvB, 1024);
    attn_kernel<<<512, 256, 0, stream>>>(qB, 512, kvB, kvB + 512, 1024, atB, 0);
    proj_res(atB, tWoX + l * SQ, dbo_xa + l * 512, xD, 512);
    ln(xD, dec_ln_g + (l * 4 + 3) * 512, dec_ln_b + (l * 4 + 3) * 512, hA);
    ffn1(hA, tW1D + l * SF, dec_b1 + l * 2048, midB);
    proj_res(midB, tW2D + l * SF, dec_b2 + l * 512, xD, 2048);
  }

  // ---------------- LM head (fused loss partials) + loss ----------------
  ln(xD, lnf_g, lnf_b, hA);
  gemm256_kernel<4, 1, 0, 0, 0, 1><<<dim3(64, 125), 512, 0, stream>>>(
      hA, tWlm, blm, nullptr, out_logits, 16384, 32000, 512, pmax, psum);
  loss_lse_kernel<<<4096, 256, 0, stream>>>(pmax, psum, out_logits, targets, rnll, rval);
  loss_final_kernel<<<1, 256, 0, stream>>>(rnll, rval, out_loss);
}

// Round 5
// 5158.666 us; speedup vs baseline: 1.1899x; 1.0534x over previous
//
#include <hip/hip_runtime.h>

typedef __attribute__((ext_vector_type(8))) short s8v;
typedef __attribute__((ext_vector_type(4))) float f4v;
using u16 = unsigned short;

__device__ __forceinline__ u16 f2bf(float f) {
  union { float f; unsigned u; } v; v.f = f;
  return (u16)((v.u + 0x7FFFu + ((v.u >> 16) & 1u)) >> 16);
}

// ---------------- positional encoding: pe[256][512] ----------------
__global__ __launch_bounds__(256) void pe_kernel(float* __restrict__ pe) {
  int i = blockIdx.x * 256 + threadIdx.x;
  int t = i >> 8, p = i & 255;
  float ex = (2.f * (float)p) / 512.f;
  float ang = (float)t * expf(-ex * 9.210340371976184f);
  pe[t * 512 + 2 * p]     = sinf(ang);
  pe[t * 512 + 2 * p + 1] = cosf(ang);
}

// -------- weight convert: f32 [R][C] -> bf16 [C][R], z-batched, dst stride --
__global__ __launch_bounds__(256) void wconv_kernel(const float* __restrict__ in,
    u16* __restrict__ out, int R, int C, size_t dstride) {
  __shared__ float tile[64][65];
  const size_t mat = (size_t)R * C;
  const float* src = in + (size_t)blockIdx.z * mat;
  u16* dst = out + (size_t)blockIdx.z * dstride;
  int r0 = blockIdx.x * 64, c0 = blockIdx.y * 64;
  int tr = threadIdx.x >> 6, tc = threadIdx.x & 63;
#pragma unroll
  for (int i = 0; i < 16; ++i)
    tile[i * 4 + tr][tc] = src[(size_t)(r0 + i * 4 + tr) * C + (c0 + tc)];
  __syncthreads();
#pragma unroll
  for (int i = 0; i < 16; ++i)
    dst[(size_t)(c0 + i * 4 + tr) * R + (r0 + tc)] = f2bf(tile[tc][i * 4 + tr]);
}

// ---------------- embedding + pe ----------------
__global__ __launch_bounds__(256) void embed_kernel(const int* __restrict__ idx,
    const float* __restrict__ emb, const float* __restrict__ pe, float* __restrict__ y) {
  int i = blockIdx.x * 256 + threadIdx.x;
  int row = i >> 7, c = (i & 127) * 4;
  int t = row & 255;
  int tok = idx[row];
  f4v e = *(const f4v*)(emb + (size_t)tok * 512 + c);
  f4v p = *(const f4v*)(pe + (size_t)t * 512 + c);
  *(f4v*)(y + (size_t)row * 512 + c) = e + p;
}

// ---------------- LayerNorm f32 -> bf16, wave per row ----------------
__global__ __launch_bounds__(256) void ln_kernel(const float* __restrict__ x,
    const float* __restrict__ g, const float* __restrict__ b, u16* __restrict__ out) {
  int row = blockIdx.x * 4 + (threadIdx.x >> 6);
  int lane = threadIdx.x & 63;
  const float* xr = x + (size_t)row * 512 + lane * 8;
  f4v v0 = *(const f4v*)xr;
  f4v v1 = *(const f4v*)(xr + 4);
  float s = v0[0] + v0[1] + v0[2] + v0[3] + v1[0] + v1[1] + v1[2] + v1[3];
#pragma unroll
  for (int o = 1; o < 64; o <<= 1) s += __shfl_xor(s, o);
  float mu = s * (1.f / 512.f);
  float q = 0.f;
#pragma unroll
  for (int j = 0; j < 4; ++j) {
    float d0 = v0[j] - mu; q += d0 * d0;
    float d1 = v1[j] - mu; q += d1 * d1;
  }
#pragma unroll
  for (int o = 1; o < 64; o <<= 1) q += __shfl_xor(q, o);
  float rs = rsqrtf(q * (1.f / 512.f) + 1e-5f);
  f4v g0 = *(const f4v*)(g + lane * 8), g1 = *(const f4v*)(g + lane * 8 + 4);
  f4v b0 = *(const f4v*)(b + lane * 8), b1 = *(const f4v*)(b + lane * 8 + 4);
  s8v ov;
#pragma unroll
  for (int j = 0; j < 4; ++j) {
    ov[j]     = (short)f2bf((v0[j] - mu) * rs * g0[j] + b0[j]);
    ov[4 + j] = (short)f2bf((v1[j] - mu) * rs * g1[j] + b1[j]);
  }
  *(s8v*)(out + (size_t)row * 512 + lane * 8) = ov;
}

// ======== GEMM: C[M,N] = A[M,K](bf16) @ Bt[N,K](bf16)^T ========
// Tile BM x BN (BM = MW*WR*16, BN = NW*64), BK=64, waves = MW*NW (each 16WR x 64),
// double-buffered LDS, 2-phase pipeline, T2 XOR swizzle (linear LDS dest,
// pre-swizzled global source slot; ds_read applies same XOR).
// f32 output: LDS-transposed coalesced f4v epilogue (optionally nontemporal),
// loss partials (max,sumexp per row per 256-col block) computed post-transpose.
template<int WR, int MW, int NW, int HAS_BIAS, int ADD_RES, int RELU,
         int OUT_BF16, int WLOSS, int NT>
__global__ __launch_bounds__(MW * NW * 64, 2) void gemm_mfma(
    const u16* __restrict__ A, const u16* __restrict__ Bt,
    const float* __restrict__ bias, const float* __restrict__ res,
    void* __restrict__ outp, int M, int N, int K,
    float* __restrict__ pmax, float* __restrict__ psum) {
  constexpr int BM = MW * WR * 16;
  constexpr int BN = NW * 64;
  constexpr int THREADS = MW * NW * 64;
  constexpr int STEP = THREADS / 8;             // staged rows per load-iter
  __shared__ __align__(16) u16 As[2][BM * 64];
  __shared__ __align__(16) u16 Bs[2][BN * 64];
  const int tid = threadIdx.x, lane = tid & 63, w = tid >> 6;
  // bijective XCD swizzle (grids always % 8 == 0 here)
  int nx = gridDim.x;
  int flat = blockIdx.y * nx + blockIdx.x;
  int per = (nx * gridDim.y) >> 3;
  int sw = (flat & 7) * per + (flat >> 3);
  int by = sw / nx, bx = sw - by * nx;
  const int m0 = bx * BM, n0 = by * BN;
  const int wm = (w / NW) * (WR * 16), wn = (w % NW) * 64;
  const int lhi = lane >> 4, llo = lane & 15;
  const int srow = tid >> 3;
  const int sl = tid & 7;                        // 16B slot within 128B row
  const int gcol = (sl ^ (srow & 7)) * 8;        // pre-swizzled global slot

  const u16* Ag = A + (size_t)(m0 + srow) * K + gcol;
  const u16* Bg = Bt + (size_t)(n0 + srow) * K + gcol;
  const size_t rstep = (size_t)STEP * K;

  auto STAGE = [&](int b, int kt) {
#pragma unroll
    for (int q = 0; q < BM / STEP; ++q)
      __builtin_amdgcn_global_load_lds(
          (const __attribute__((address_space(1))) void*)(Ag + q * rstep + kt),
          (__attribute__((address_space(3))) void*)(&As[b][(q * STEP + srow) * 64 + sl * 8]),
          16, 0, 0);
#pragma unroll
    for (int q = 0; q < BN / STEP; ++q)
      __builtin_amdgcn_global_load_lds(
          (const __attribute__((address_space(1))) void*)(Bg + q * rstep + kt),
          (__attribute__((address_space(3))) void*)(&Bs[b][(q * STEP + srow) * 64 + sl * 8]),
          16, 0, 0);
  };
  const int sx = llo & 7;

  f4v acc[WR][4] = {};
  const int nk = K >> 6;
  STAGE(0, 0);
  asm volatile("s_waitcnt vmcnt(0)" ::: "memory");
  __builtin_amdgcn_s_barrier();
  __builtin_amdgcn_sched_barrier(0);
  int cur = 0;
  for (int t = 0; t < nk; ++t) {
    if (t + 1 < nk) STAGE(cur ^ 1, (t + 1) * 64);
#pragma unroll
    for (int kk = 0; kk < 2; ++kk) {
      s8v af[WR], bfv[4];
#pragma unroll
      for (int i = 0; i < WR; ++i)
        af[i] = *(const s8v*)&As[cur][(wm + i * 16 + llo) * 64 + (((kk * 4 + lhi) ^ sx) * 8)];
#pragma unroll
      for (int j = 0; j < 4; ++j)
        bfv[j] = *(const s8v*)&Bs[cur][(wn + j * 16 + llo) * 64 + (((kk * 4 + lhi) ^ sx) * 8)];
      __builtin_amdgcn_s_setprio(1);
#pragma unroll
      for (int i = 0; i < WR; ++i)
#pragma unroll
        for (int j = 0; j < 4; ++j)
          acc[i][j] = __builtin_amdgcn_mfma_f32_16x16x32_bf16(af[i], bfv[j], acc[i][j], 0, 0, 0);
      __builtin_amdgcn_s_setprio(0);
    }
    asm volatile("s_waitcnt vmcnt(0)" ::: "memory");
    __builtin_amdgcn_s_barrier();
    __builtin_amdgcn_sched_barrier(0);
    cur ^= 1;
  }

  // ---- epilogue (D row = (l>>4)*4 + r, col = l&15 — verified layout) ----
  if (OUT_BF16) {
    float bvj[4];
#pragma unroll
    for (int j = 0; j < 4; ++j)
      bvj[j] = HAS_BIAS ? bias[n0 + wn + j * 16 + llo] : 0.f;
#pragma unroll
    for (int i = 0; i < WR; ++i) {
#pragma unroll
      for (int j = 0; j < 4; ++j) {
        int col = n0 + wn + j * 16 + llo;
#pragma unroll
        for (int r = 0; r < 4; ++r) {
          int row = m0 + wm + i * 16 + lhi * 4 + r;
          float v = acc[i][j][r] + bvj[j];
          if (RELU) v = fmaxf(v, 0.f);
          ((u16*)outp)[(size_t)row * N + col] = f2bf(v);
        }
      }
    }
  } else {
    // transposed coalesced f32 path: wave-private LDS [16][68] f32
    float* lb = (float*)&As[0][0];
    float* wbuf = lb + w * 1088;
    f4v bias4 = {0.f, 0.f, 0.f, 0.f};
    if (HAS_BIAS) bias4 = *(const f4v*)(bias + n0 + wn + llo * 4);
    float* lbm = lb + 9216;
    float* lbs = lb + 10240;
#pragma unroll
    for (int i = 0; i < WR; ++i) {
#pragma unroll
      for (int j = 0; j < 4; ++j)
#pragma unroll
        for (int r = 0; r < 4; ++r)
          wbuf[(lhi * 4 + r) * 68 + j * 16 + llo] = acc[i][j][r];
      asm volatile("s_waitcnt lgkmcnt(0)" ::: "memory");
      __builtin_amdgcn_sched_barrier(0);
#pragma unroll
      for (int p = 0; p < 4; ++p) {
        int r16 = p * 4 + lhi;
        f4v v4 = *(const f4v*)&wbuf[r16 * 68 + llo * 4];
        v4 += bias4;
        int grow = m0 + wm + i * 16 + r16;
        int gcol4 = n0 + wn + llo * 4;
        if (ADD_RES) v4 += *(const f4v*)(res + (size_t)grow * N + gcol4);
        if (RELU) {
          v4[0] = fmaxf(v4[0], 0.f); v4[1] = fmaxf(v4[1], 0.f);
          v4[2] = fmaxf(v4[2], 0.f); v4[3] = fmaxf(v4[3], 0.f);
        }
        float* dst = (float*)outp + (size_t)grow * N + gcol4;
        if (NT) __builtin_nontemporal_store(v4, (f4v*)dst);
        else    *(f4v*)dst = v4;
        if (WLOSS) {
          float mx = fmaxf(fmaxf(v4[0], v4[1]), fmaxf(v4[2], v4[3]));
          mx = fmaxf(mx, __shfl_xor(mx, 1));
          mx = fmaxf(mx, __shfl_xor(mx, 2));
          mx = fmaxf(mx, __shfl_xor(mx, 4));
          mx = fmaxf(mx, __shfl_xor(mx, 8));
          float sum = __expf(v4[0] - mx) + __expf(v4[1] - mx)
                    + __expf(v4[2] - mx) + __expf(v4[3] - mx);
          sum += __shfl_xor(sum, 1); sum += __shfl_xor(sum, 2);
          sum += __shfl_xor(sum, 4); sum += __shfl_xor(sum, 8);
          if (llo == 0) {
            int lr = wm + i * 16 + r16;
            lbm[lr * 4 + (wn >> 6)] = mx;
            lbs[lr * 4 + (wn >> 6)] = sum;
          }
        }
      }
      asm volatile("s_waitcnt lgkmcnt(0)" ::: "memory");
      __builtin_amdgcn_sched_barrier(0);
    }
    if (WLOSS) {
      __syncthreads();
      if (tid < 256) {
        float m = lbm[tid * 4];
        m = fmaxf(fmaxf(m, lbm[tid * 4 + 1]), fmaxf(lbm[tid * 4 + 2], lbm[tid * 4 + 3]));
        float ss = lbs[tid * 4 + 0] * __expf(lbm[tid * 4 + 0] - m)
                 + lbs[tid * 4 + 1] * __expf(lbm[tid * 4 + 1] - m)
                 + lbs[tid * 4 + 2] * __expf(lbm[tid * 4 + 2] - m)
                 + lbs[tid * 4 + 3] * __expf(lbm[tid * 4 + 3] - m);
        int ntile = N >> 8;
        pmax[(size_t)(m0 + tid) * ntile + by] = m;
        psum[(size_t)(m0 + tid) * ntile + by] = ss;
      }
    }
  }
}

// -------- fused attention, one (b,h) per block, T=256, hd=64, strided QKV ----
__global__ __launch_bounds__(256) void attn_kernel(
    const u16* __restrict__ Qp, int qs, const u16* __restrict__ Kp,
    const u16* __restrict__ Vp, int kvs, u16* __restrict__ Ob, int causal) {
  __shared__ __align__(16) u16 Ks[256][72];
  __shared__ __align__(16) u16 Vt[64][264];
  __shared__ __align__(16) u16 Ps[4][16][264];
  const int tid = threadIdx.x, lane = tid & 63, w = tid >> 6;
  const int b = blockIdx.x >> 3, h = blockIdx.x & 7;
  const size_t qbase  = (size_t)b * 256 * qs  + (size_t)h * 64;
  const size_t kvbase = (size_t)b * 256 * kvs + (size_t)h * 64;
  const size_t obase  = (size_t)b * 256 * 512 + (size_t)h * 64;
  {
    int t0 = tid >> 3, d0 = (tid & 7) * 8;
#pragma unroll
    for (int it = 0; it < 8; ++it) {
      int t = it * 32 + t0;
      s8v kv = *(const s8v*)(Kp + kvbase + (size_t)t * kvs + d0);
      *(s8v*)&Ks[t][d0] = kv;
      s8v vv = *(const s8v*)(Vp + kvbase + (size_t)t * kvs + d0);
#pragma unroll
      for (int j = 0; j < 8; ++j) Vt[d0 + j][t] = (u16)vv[j];
    }
  }
  __syncthreads();
  const int lhi = lane >> 4, llo = lane & 15;
  for (int qc = 0; qc < 4; ++qc) {
    const int qr0 = w * 64 + qc * 16;
    s8v aq0 = *(const s8v*)(Qp + qbase + (size_t)(qr0 + llo) * qs + lhi * 8);
    s8v aq1 = *(const s8v*)(Qp + qbase + (size_t)(qr0 + llo) * qs + 32 + lhi * 8);
    f4v S[16];
#pragma unroll
    for (int c = 0; c < 16; ++c) {
      s8v bk0 = *(const s8v*)&Ks[c * 16 + llo][lhi * 8];
      s8v bk1 = *(const s8v*)&Ks[c * 16 + llo][32 + lhi * 8];
      f4v z = {0.f, 0.f, 0.f, 0.f};
      z = __builtin_amdgcn_mfma_f32_16x16x32_bf16(aq0, bk0, z, 0, 0, 0);
      S[c] = __builtin_amdgcn_mfma_f32_16x16x32_bf16(aq1, bk1, z, 0, 0, 0);
    }
#pragma unroll
    for (int r = 0; r < 4; ++r) {
      const int tq = qr0 + lhi * 4 + r;
      float mx = -1e30f;
#pragma unroll
      for (int c = 0; c < 16; ++c) {
        float s = S[c][r] * 0.125f;
        if (causal && (c * 16 + llo) > tq) s = -1e30f;
        S[c][r] = s;
        mx = fmaxf(mx, s);
      }
      mx = fmaxf(mx, __shfl_xor(mx, 1));
      mx = fmaxf(mx, __shfl_xor(mx, 2));
      mx = fmaxf(mx, __shfl_xor(mx, 4));
      mx = fmaxf(mx, __shfl_xor(mx, 8));
      float sum = 0.f;
#pragma unroll
      for (int c = 0; c < 16; ++c) { float p = __expf(S[c][r] - mx); S[c][r] = p; sum += p; }
      sum += __shfl_xor(sum, 1); sum += __shfl_xor(sum, 2);
      sum += __shfl_xor(sum, 4); sum += __shfl_xor(sum, 8);
      float inv = 1.f / sum;
#pragma unroll
      for (int c = 0; c < 16; ++c)
        Ps[w][lhi * 4 + r][c * 16 + llo] = f2bf(S[c][r] * inv);
    }
    asm volatile("s_waitcnt lgkmcnt(0)" ::: "memory");
    f4v o[4] = {};
#pragma unroll
    for (int kb = 0; kb < 8; ++kb) {
      s8v pa = *(const s8v*)&Ps[w][llo][kb * 32 + lhi * 8];
#pragma unroll
      for (int nb = 0; nb < 4; ++nb) {
        s8v bv = *(const s8v*)&Vt[nb * 16 + llo][kb * 32 + lhi * 8];
        o[nb] = __builtin_amdgcn_mfma_f32_16x16x32_bf16(pa, bv, o[nb], 0, 0, 0);
      }
    }
#pragma unroll
    for (int nb = 0; nb < 4; ++nb)
#pragma unroll
      for (int r = 0; r < 4; ++r)
        Ob[obase + (size_t)(qr0 + lhi * 4 + r) * 512 + nb * 16 + llo] = f2bf(o[nb][r]);
  }
}

// ---------------- loss: merge per-tile partials -> per-row nll ----------------
__global__ __launch_bounds__(256) void loss_lse_kernel(const float* __restrict__ pmax,
    const float* __restrict__ psum, const float* __restrict__ logits,
    const int* __restrict__ tgt, float* __restrict__ nll, float* __restrict__ valid) {
  const int w = threadIdx.x >> 6, lane = threadIdx.x & 63;
  const int row = blockIdx.x * 4 + w;
  float m = -1e30f, s = 0.f;
  for (int e = lane; e < 125; e += 64) {
    float pm = pmax[(size_t)row * 125 + e], ps = psum[(size_t)row * 125 + e];
    if (pm > m) { s = s * __expf(m - pm) + ps; m = pm; }
    else          s += ps * __expf(pm - m);
  }
#pragma unroll
  for (int o = 1; o < 64; o <<= 1) {
    float om = __shfl_xor(m, o), os = __shfl_xor(s, o);
    float mm = fmaxf(m, om);
    s = s * __expf(m - mm) + os * __expf(om - mm);
    m = mm;
  }
  if (lane == 0) {
    int t = tgt[row];
    float lse = m + logf(s);
    float v = (t != 1) ? 1.f : 0.f;
    nll[row] = v * (lse - logits[(size_t)row * 32000 + t]);
    valid[row] = v;
  }
}

__global__ __launch_bounds__(256) void loss_final_kernel(const float* __restrict__ nll,
    const float* __restrict__ valid, float* __restrict__ out) {
  __shared__ float sa[256], sb[256];
  int tid = threadIdx.x;
  float s = 0.f, c = 0.f;
  for (int i = tid; i < 16384; i += 256) { s += nll[i]; c += valid[i]; }
  sa[tid] = s; sb[tid] = c;
  __syncthreads();
  for (int st = 128; st > 0; st >>= 1) {
    if (tid < st) { sa[tid] += sa[tid + st]; sb[tid] += sb[tid + st]; }
    __syncthreads();
  }
  if (tid == 0) out[0] = sa[0] / fmaxf(sb[0], 1.f);
}

// =============================== host ===============================
extern "C" void kernel_launch(void* const* d_in, const int* in_sizes, int n_in,
                              void* d_out, int out_size, void* d_ws, size_t ws_size,
                              hipStream_t stream) {
  (void)in_sizes; (void)n_in; (void)out_size; (void)ws_size;
  const int* idx       = (const int*)d_in[0];
  const int* idx_enc   = (const int*)d_in[1];
  const int* targets   = (const int*)d_in[2];
  const float* emb_dec = (const float*)d_in[3];
  const float* emb_enc = (const float*)d_in[4];
  const float* enc_Wq  = (const float*)d_in[5];
  const float* enc_Wk  = (const float*)d_in[6];
  const float* enc_Wv  = (const float*)d_in[7];
  const float* enc_Wo  = (const float*)d_in[8];
  const float* enc_bo  = (const float*)d_in[9];
  const float* enc_ln_g = (const float*)d_in[10];
  const float* enc_ln_b = (const float*)d_in[11];
  const float* enc_W1  = (const float*)d_in[12];
  const float* enc_b1  = (const float*)d_in[13];
  const float* enc_W2  = (const float*)d_in[14];
  const float* enc_b2  = (const float*)d_in[15];
  const float* dWq_sa  = (const float*)d_in[16];
  const float* dWk_sa  = (const float*)d_in[17];
  const float* dWv_sa  = (const float*)d_in[18];
  const float* dWo_sa  = (const float*)d_in[19];
  const float* dbo_sa  = (const float*)d_in[20];
  const float* dWq_xa  = (const float*)d_in[21];
  const float* dWk_xa  = (const float*)d_in[22];
  const float* dWv_xa  = (const float*)d_in[23];
  const float* dWo_xa  = (const float*)d_in[24];
  const float* dbo_xa  = (const float*)d_in[25];
  const float* dec_ln_g = (const float*)d_in[26];
  const float* dec_ln_b = (const float*)d_in[27];
  const float* dec_W1  = (const float*)d_in[28];
  const float* dec_b1  = (const float*)d_in[29];
  const float* dec_W2  = (const float*)d_in[30];
  const float* dec_b2  = (const float*)d_in[31];
  const float* lnf_g   = (const float*)d_in[32];
  const float* lnf_b   = (const float*)d_in[33];
  const float* Wlm     = (const float*)d_in[34];
  const float* blm     = (const float*)d_in[35];
  float* out_logits = (float*)d_out;
  float* out_loss   = out_logits + (size_t)16384 * 32000;

  size_t off = 0;
  auto alloc = [&](size_t bytes) -> char* {
    char* p = (char*)d_ws + off;
    off += (bytes + 255) & ~(size_t)255;
    return p;
  };
  const size_t SQ = 512 * 512, SF = 512 * 2048;
  u16* tWqkvE = (u16*)alloc(6 * 3 * SQ * 2);
  u16* tWoE   = (u16*)alloc(6 * SQ * 2);
  u16* tW1E   = (u16*)alloc(6 * SF * 2);
  u16* tW2E   = (u16*)alloc(6 * SF * 2);
  u16* tWqkvS = (u16*)alloc(6 * 3 * SQ * 2);
  u16* tWoS   = (u16*)alloc(6 * SQ * 2);
  u16* tWqX   = (u16*)alloc(6 * SQ * 2);
  u16* tWkvX  = (u16*)alloc(6 * 2 * SQ * 2);
  u16* tWoX   = (u16*)alloc(6 * SQ * 2);
  u16* tW1D   = (u16*)alloc(6 * SF * 2);
  u16* tW2D   = (u16*)alloc(6 * SF * 2);
  u16* tWlm   = (u16*)alloc((size_t)32000 * 512 * 2);
  float* pe   = (float*)alloc(256 * 512 * 4);
  float* yE   = (float*)alloc((size_t)16384 * 512 * 4);
  float* xD   = (float*)alloc((size_t)16384 * 512 * 4);
  u16* hA     = (u16*)alloc((size_t)16384 * 512 * 2);
  u16* hB     = (u16*)alloc((size_t)16384 * 512 * 2);
  u16* qkvB   = (u16*)alloc((size_t)16384 * 1536 * 2);
  u16* qB     = (u16*)alloc((size_t)16384 * 512 * 2);
  u16* kvB    = (u16*)alloc((size_t)16384 * 1024 * 2);
  u16* atB    = (u16*)alloc((size_t)16384 * 512 * 2);
  u16* midB   = (u16*)alloc((size_t)16384 * 2048 * 2);
  float* pmax = (float*)alloc((size_t)16384 * 125 * 4);
  float* psum = (float*)alloc((size_t)16384 * 125 * 4);
  float* rnll = (float*)alloc(16384 * 4);
  float* rval = (float*)alloc(16384 * 4);

  // ---- weight conversion (every call; deterministic) ----
  dim3 tb(256);
  const size_t S3 = 3 * SQ, S2 = 2 * SQ;
  wconv_kernel<<<dim3(8, 8, 6), tb, 0, stream>>>(enc_Wq, tWqkvE + 0 * SQ, 512, 512, S3);
  wconv_kernel<<<dim3(8, 8, 6), tb, 0, stream>>>(enc_Wk, tWqkvE + 1 * SQ, 512, 512, S3);
  wconv_kernel<<<dim3(8, 8, 6), tb, 0, stream>>>(enc_Wv, tWqkvE + 2 * SQ, 512, 512, S3);
  wconv_kernel<<<dim3(8, 8, 6), tb, 0, stream>>>(enc_Wo, tWoE, 512, 512, SQ);
  wconv_kernel<<<dim3(8, 32, 6), tb, 0, stream>>>(enc_W1, tW1E, 512, 2048, SF);
  wconv_kernel<<<dim3(32, 8, 6), tb, 0, stream>>>(enc_W2, tW2E, 2048, 512, SF);
  wconv_kernel<<<dim3(8, 8, 6), tb, 0, stream>>>(dWq_sa, tWqkvS + 0 * SQ, 512, 512, S3);
  wconv_kernel<<<dim3(8, 8, 6), tb, 0, stream>>>(dWk_sa, tWqkvS + 1 * SQ, 512, 512, S3);
  wconv_kernel<<<dim3(8, 8, 6), tb, 0, stream>>>(dWv_sa, tWqkvS + 2 * SQ, 512, 512, S3);
  wconv_kernel<<<dim3(8, 8, 6), tb, 0, stream>>>(dWo_sa, tWoS, 512, 512, SQ);
  wconv_kernel<<<dim3(8, 8, 6), tb, 0, stream>>>(dWq_xa, tWqX, 512, 512, SQ);
  wconv_kernel<<<dim3(8, 8, 6), tb, 0, stream>>>(dWk_xa, tWkvX + 0 * SQ, 512, 512, S2);
  wconv_kernel<<<dim3(8, 8, 6), tb, 0, stream>>>(dWv_xa, tWkvX + 1 * SQ, 512, 512, S2);
  wconv_kernel<<<dim3(8, 8, 6), tb, 0, stream>>>(dWo_xa, tWoX, 512, 512, SQ);
  wconv_kernel<<<dim3(8, 32, 6), tb, 0, stream>>>(dec_W1, tW1D, 512, 2048, SF);
  wconv_kernel<<<dim3(32, 8, 6), tb, 0, stream>>>(dec_W2, tW2D, 2048, 512, SF);
  wconv_kernel<<<dim3(8, 500, 1), tb, 0, stream>>>(Wlm, tWlm, 512, 32000, (size_t)0);
  pe_kernel<<<256, 256, 0, stream>>>(pe);

  auto ln = [&](const float* xin, const float* g, const float* bb, u16* o) {
    ln_kernel<<<4096, 256, 0, stream>>>(xin, g, bb, o);
  };
  // 128x128-tile instances (4 waves) for small-N; 256x256 (8 waves) for big-N.
  auto g_bf16_sm = [&](const u16* Ap, const u16* Bp, u16* Op, int N) {
    gemm_mfma<4, 2, 2, 0, 0, 0, 1, 0, 0><<<dim3(128, N / 128), 256, 0, stream>>>(
        Ap, Bp, nullptr, nullptr, Op, 16384, N, 512, nullptr, nullptr);
  };
  auto proj_res = [&](const u16* Ap, const u16* Bp, const float* bi, float* xr, int K) {
    gemm_mfma<4, 2, 2, 1, 1, 0, 0, 0, 0><<<dim3(128, 4), 256, 0, stream>>>(
        Ap, Bp, bi, xr, xr, 16384, 512, K, nullptr, nullptr);
  };
  auto ffn1 = [&](const u16* Ap, const u16* Bp, const float* bi, u16* Op) {
    gemm_mfma<8, 2, 4, 1, 0, 1, 1, 0, 0><<<dim3(64, 8), 512, 0, stream>>>(
        Ap, Bp, bi, nullptr, Op, 16384, 2048, 512, nullptr, nullptr);
  };

  // ---------------- encoder ----------------
  embed_kernel<<<8192, 256, 0, stream>>>(idx_enc, emb_enc, pe, yE);
  for (int l = 0; l < 6; ++l) {
    ln(yE, enc_ln_g + (l * 2 + 0) * 512, enc_ln_b + (l * 2 + 0) * 512, hA);
    g_bf16_sm(hA, tWqkvE + l * S3, qkvB, 1536);
    attn_kernel<<<512, 256, 0, stream>>>(qkvB, 1536, qkvB + 512, qkvB + 1024, 1536, atB, 0);
    proj_res(atB, tWoE + l * SQ, enc_bo + l * 512, yE, 512);
    ln(yE, enc_ln_g + (l * 2 + 1) * 512, enc_ln_b + (l * 2 + 1) * 512, hA);
    ffn1(hA, tW1E + l * SF, enc_b1 + l * 2048, midB);
    proj_res(midB, tW2E + l * SF, enc_b2 + l * 512, yE, 2048);
  }

  // ---------------- decoder ----------------
  embed_kernel<<<8192, 256, 0, stream>>>(idx, emb_dec, pe, xD);
  for (int l = 0; l < 6; ++l) {
    ln(xD, dec_ln_g + (l * 4 + 0) * 512, dec_ln_b + (l * 4 + 0) * 512, hA);
    g_bf16_sm(hA, tWqkvS + l * S3, qkvB, 1536);
    attn_kernel<<<512, 256, 0, stream>>>(qkvB, 1536, qkvB + 512, qkvB + 1024, 1536, atB, 1);
    proj_res(atB, tWoS + l * SQ, dbo_sa + l * 512, xD, 512);
    ln(xD, dec_ln_g + (l * 4 + 1) * 512, dec_ln_b + (l * 4 + 1) * 512, hA);
    ln(yE, dec_ln_g + (l * 4 + 2) * 512, dec_ln_b + (l * 4 + 2) * 512, hB);
    g_bf16_sm(hA, tWqX + l * SQ, qB, 512);
    g_bf16_sm(hB, tWkvX + l * S2, kvB, 1024);
    attn_kernel<<<512, 256, 0, stream>>>(qB, 512, kvB, kvB + 512, 1024, atB, 0);
    proj_res(atB, tWoX + l * SQ, dbo_xa + l * 512, xD, 512);
    ln(xD, dec_ln_g + (l * 4 + 3) * 512, dec_ln_b + (l * 4 + 3) * 512, hA);
    ffn1(hA, tW1D + l * SF, dec_b1 + l * 2048, midB);
    proj_res(midB, tW2D + l * SF, dec_b2 + l * 512, xD, 2048);
  }

  // ---------------- LM head (fused loss partials, nt logits) + loss ----------------
  ln(xD, lnf_g, lnf_b, hA);
  gemm_mfma<8, 2, 4, 1, 0, 0, 0, 1, 1><<<dim3(64, 125), 512, 0, stream>>>(
      hA, tWlm, blm, nullptr, out_logits, 16384, 32000, 512, pmax, psum);
  loss_lse_kernel<<<4096, 256, 0, stream>>>(pmax, psum, out_logits, targets, rnll, rval);
  loss_final_kernel<<<1, 256, 0, stream>>>(rnll, rval, out_loss);
}